// Round 11
// baseline (626.495 us; speedup 1.0000x reference)
//
#include <hip/hip_runtime.h>
#include <hip/hip_fp16.h>
#include <cstdint>
#include <cstddef>

#define N_NODES 100000
#define N_EDGES 1600000
#define D 128
#define NLAYERS 3
#define NSCAN 391     // ceil(100000/256) scan blocks

typedef float f2v __attribute__((ext_vector_type(2)));
typedef _Float16 f16x8 __attribute__((ext_vector_type(8)));
typedef float f32x4 __attribute__((ext_vector_type(4)));
typedef unsigned u32x4 __attribute__((ext_vector_type(4)));

// ---------------- CSR build via global atomics ----------------
// R10 post-mortem: the bucket-sort CSR (hist/btot/bscan/hoff/scatter/fill2)
// cost ~135us, with btot/hoff at 13 blocks (95% GPU idle) and hist/scatter at
// 128 blocks (50% idle). Global-atomic CSR: 1.6M non-returning atomics over
// 100K degree counters (16/counter avg, low contention), a 3-dispatch scan,
// and 1.6M returning atomics for the scatter. Order within a node is
// arbitrary — same as the bucket sort; the aggregation sum is commutative.

__global__ void zero_kernel(int* __restrict__ deg, int n) {
    int i = blockIdx.x * 256 + threadIdx.x;
    if (i < n) deg[i] = 0;
}

__global__ void deg_kernel(const int* __restrict__ col, int* __restrict__ deg) {
    int i = blockIdx.x * 256 + threadIdx.x;  // e = 6250*256 exactly
    atomicAdd(&deg[col[i]], 1);              // non-returning form
}

// Per-256-chunk exclusive scan; chunk-local result into offsets, totals out.
__global__ __launch_bounds__(256) void scan1_kernel(const int* __restrict__ deg,
                                                    int* __restrict__ offsets,
                                                    int* __restrict__ totals, int n) {
    __shared__ int lsum[256];
    int b = blockIdx.x, t = threadIdx.x;
    int idx = b * 256 + t;
    int d = (idx < n) ? deg[idx] : 0;
    lsum[t] = d;
    __syncthreads();
    for (int off = 1; off < 256; off <<= 1) {
        int x = (t >= off) ? lsum[t - off] : 0;
        __syncthreads();
        lsum[t] += x;
        __syncthreads();
    }
    if (idx < n) offsets[idx] = lsum[t] - d;  // chunk-exclusive
    if (t == 255) totals[b] = lsum[255];
}

// Exclusive scan of the NSCAN chunk totals (in place). One block.
__global__ __launch_bounds__(512) void scan2_kernel(int* __restrict__ totals, int nb) {
    __shared__ int lsum[512];
    int t = threadIdx.x;
    int d = (t < nb) ? totals[t] : 0;
    lsum[t] = d;
    __syncthreads();
    for (int off = 1; off < 512; off <<= 1) {
        int x = (t >= off) ? lsum[t - off] : 0;
        __syncthreads();
        lsum[t] += x;
        __syncthreads();
    }
    if (t < nb) totals[t] = lsum[t] - d;
}

// Add chunk bases; produce offsets, scatter cursors, and dinv.
__global__ __launch_bounds__(256) void scan3_kernel(const int* __restrict__ deg,
                                                    int* __restrict__ offsets,
                                                    const int* __restrict__ totals,
                                                    int* __restrict__ cur,
                                                    float* __restrict__ dinv, int n, int e) {
    int b = blockIdx.x, t = threadIdx.x;
    int idx = b * 256 + t;
    if (idx < n) {
        int off = offsets[idx] + totals[b];
        offsets[idx] = off;
        cur[idx] = off;
        dinv[idx] = rsqrtf((float)(deg[idx] + 1));  // +1 self loop
    }
    if (b == 0 && t == 0) offsets[n] = e;
}

__global__ void scatter2_kernel(const int* __restrict__ row, const int* __restrict__ col,
                                int* __restrict__ cur, int* __restrict__ src) {
    int i = blockIdx.x * 256 + threadIdx.x;  // e = 6250*256 exactly
    int pos = atomicAdd(&cur[col[i]], 1);
    src[pos] = row[i];
}

// ---------------- per-layer kernels ----------------

// Cast + pre-scale: xs[v] = fp16(dinv[v] * emb[v]). Pre-scaling removes the
// per-edge dinv[src] gather + multiply from the agg inner loop.
__global__ void cast_kernel(const float2* __restrict__ in, const float* __restrict__ dinv,
                            __half2* __restrict__ out, int n2) {
    int i = blockIdx.x * 256 + threadIdx.x;
    if (i < n2) {
        float d = dinv[i >> 6];  // wave-uniform (64 half2 per node)
        float2 v = in[i];
        out[i] = __floats2half2_rn(d * v.x, d * v.y);
    }
}

// W pre-split for the hi/lo fp16 MFMA: WhT/WlT[l][col][k] (transposed,
// fragment-ready). w = wh + wl with wh=fp16(w), wl=fp16(w-wh): 22-bit
// combined mantissa -> GEMM error ~2^-20, far below the fp16-gather noise.
__global__ void wsplit_kernel(const float* __restrict__ W,
                              _Float16* __restrict__ Wh, _Float16* __restrict__ Wl) {
    int c = blockIdx.x, l = blockIdx.y, k = threadIdx.x;  // 128 threads
    float w = W[(size_t)l * 16384 + k * 128 + c];
    _Float16 h = (_Float16)w;
    float r = w - (float)h;
    Wh[(size_t)l * 16384 + c * 128 + k] = h;
    Wl[(size_t)l * 16384 + c * 128 + k] = (_Float16)r;
}

// UNFUSED aggregation (R5-verified structure; R8 showed fusing costs 2x
// gather BW). One 64-thread block (=1 wave) per node; xs PRE-SCALED:
//   a[v] = dinv[v] * ( xs[v] + sum_e xs[src_e] ), fp32 accum.
// R10 changes: (1) 16-deep main unroll (16 outstanding 256B gathers/wave,
// was 8 — Little's law headroom, VGPR stays < 64); (2) `vbase` so the grid
// can be split into two 50K dispatches — makes the ~50us gemm visible in
// the top-5 counter table next round (it currently hides under 61us aggs).
// Output written as hi/lo fp16 planes (Ah, Al), NT-stored.
__global__ void agg_kernel(const __half2* __restrict__ xs, const int* __restrict__ offs,
                           unsigned* __restrict__ Ah, unsigned* __restrict__ Al,
                           const float* __restrict__ dinv, const int* __restrict__ src,
                           int vbase) {
    int v = vbase + blockIdx.x;
    int f = threadIdx.x;  // 0..63
    float dv = dinv[v];
    float2 a0 = __half22float2(xs[(size_t)v * 64 + f]);  // self term (already scaled)
    float ax = a0.x;
    float ay = a0.y;
    int i = offs[v], s1 = offs[v + 1];
    for (; i + 15 < s1; i += 16) {  // 16-deep main
        int s[16];
#pragma unroll
        for (int j = 0; j < 16; j++) s[j] = src[i + j];
        float2 x[16];
#pragma unroll
        for (int j = 0; j < 16; j++) x[j] = __half22float2(xs[(size_t)s[j] * 64 + f]);
#pragma unroll
        for (int j = 0; j < 16; j++) {
            ax += x[j].x;
            ay += x[j].y;
        }
    }
    if (i + 7 < s1) {  // 8-deep
        int s[8];
#pragma unroll
        for (int j = 0; j < 8; j++) s[j] = src[i + j];
        float2 x[8];
#pragma unroll
        for (int j = 0; j < 8; j++) x[j] = __half22float2(xs[(size_t)s[j] * 64 + f]);
#pragma unroll
        for (int j = 0; j < 8; j++) {
            ax += x[j].x;
            ay += x[j].y;
        }
        i += 8;
    }
    if (i < s1) {  // masked tail group
        int last = s1 - 1;
        int s[8];
        float m[8];
#pragma unroll
        for (int j = 0; j < 8; j++) {
            int idx = i + j;
            bool in = idx < s1;
            s[j] = src[in ? idx : last];
            m[j] = in ? 1.0f : 0.0f;
        }
        float2 x[8];
#pragma unroll
        for (int j = 0; j < 8; j++) x[j] = __half22float2(xs[(size_t)s[j] * 64 + f]);
#pragma unroll
        for (int j = 0; j < 8; j++) {
            ax += m[j] * x[j].x;
            ay += m[j] * x[j].y;
        }
    }
    float rx = dv * ax, ry = dv * ay;
    __half2 h2 = __floats2half2_rn(rx, ry);
    float2 hb = __half22float2(h2);
    __half2 l2 = __floats2half2_rn(rx - hb.x, ry - hb.y);
    __builtin_nontemporal_store(__builtin_bit_cast(unsigned, h2), Ah + (size_t)v * 64 + f);
    __builtin_nontemporal_store(__builtin_bit_cast(unsigned, l2), Al + (size_t)v * 64 + f);
}

// out[M x 128] = relu(A[M x 128] @ W[128 x 128] + bias) via hi/lo fp16 MFMA.
// BM=32, 3125 blocks, 17.4KB LDS, W-frags from global L2. UNCHANGED from
// R10 (neutral vs BM=128; both ~50us/layer — diagnosis pending the counter
// visibility this round's agg-split buys).
__global__ __launch_bounds__(256, 6) void gemm_mfma_kernel(
    const _Float16* __restrict__ Ahp, const _Float16* __restrict__ Alp,
    const _Float16* __restrict__ Whp, const _Float16* __restrict__ Wlp,  // [col][k]
    const float* __restrict__ bias, float* __restrict__ out,
    __half2* __restrict__ xs_out, const float* __restrict__ dinv,
    int write_h, int write_out) {
    __shared__ _Float16 sA[2][32][136];  // [plane][row][16 kg * 8 + 8 pad] = 17.4 KB
    int t = threadIdx.x;
    int f = t & 63;   // lane
    int w = t >> 6;   // wave 0..3 -> cols w*32 .. w*32+31
    int row0 = blockIdx.x * 32;

    // ---- stage A tile: 1024 qwords (2 planes x 32 rows x 16), 4 per thread ----
    const u32x4* Aq[2] = {(const u32x4*)Ahp, (const u32x4*)Alp};
#pragma unroll
    for (int i = 0; i < 4; i++) {
        int qid = t + 256 * i;          // 0..1023, bijective over (p, r, k2)
        int p = qid >> 9;
        int rem = qid & 511;
        int r = rem >> 4;               // 0..31
        int k2 = rem & 15;              // 16B k-group
        u32x4 v = __builtin_nontemporal_load(&Aq[p][(size_t)(row0 + r) * 16 + k2]);
        *(u32x4*)&sA[p][r][k2 * 8] = v;
    }
    __syncthreads();

    // ---- MFMA: rows 0..31 (2 m-frags) x wave's 32 cols (2 col-frags) ----
    int lrow = f & 15, kg = f >> 4;
    f32x4 acc[2][2];  // [m][c]
#pragma unroll
    for (int m = 0; m < 2; m++)
#pragma unroll
        for (int c = 0; c < 2; c++) acc[m][c] = (f32x4){0.f, 0.f, 0.f, 0.f};

#pragma unroll
    for (int ks = 0; ks < 4; ks++) {
        int g = ks * 4 + kg;  // 8-element k-group index
        f16x8 a0h = *(const f16x8*)&sA[0][lrow][g * 8];
        f16x8 a0l = *(const f16x8*)&sA[1][lrow][g * 8];
        f16x8 a1h = *(const f16x8*)&sA[0][16 + lrow][g * 8];
        f16x8 a1l = *(const f16x8*)&sA[1][16 + lrow][g * 8];
#pragma unroll
        for (int c = 0; c < 2; c++) {
            int col = w * 32 + c * 16 + lrow;
            f16x8 bh = *(const f16x8*)&Whp[(size_t)col * 128 + g * 8];
            f16x8 bl = *(const f16x8*)&Wlp[(size_t)col * 128 + g * 8];
            acc[0][c] = __builtin_amdgcn_mfma_f32_16x16x32_f16(a0h, bh, acc[0][c], 0, 0, 0);
            acc[0][c] = __builtin_amdgcn_mfma_f32_16x16x32_f16(a0l, bh, acc[0][c], 0, 0, 0);
            acc[0][c] = __builtin_amdgcn_mfma_f32_16x16x32_f16(a0h, bl, acc[0][c], 0, 0, 0);
            acc[1][c] = __builtin_amdgcn_mfma_f32_16x16x32_f16(a1h, bh, acc[1][c], 0, 0, 0);
            acc[1][c] = __builtin_amdgcn_mfma_f32_16x16x32_f16(a1l, bh, acc[1][c], 0, 0, 0);
            acc[1][c] = __builtin_amdgcn_mfma_f32_16x16x32_f16(a1h, bl, acc[1][c], 0, 0, 0);
        }
    }

    // ---- epilogue: bias + relu; C/D frag: col=lane&15, row=(lane>>4)*4+reg ----
    float bcol[2];
    bcol[0] = bias[w * 32 + 0 * 16 + lrow];
    bcol[1] = bias[w * 32 + 1 * 16 + lrow];
#pragma unroll
    for (int m = 0; m < 2; m++) {
        int rbase = row0 + m * 16 + kg * 4;
#pragma unroll
        for (int j = 0; j < 4; j++) {
            int rowi = rbase + j;
            float dvr = write_h ? dinv[rowi] : 0.f;
#pragma unroll
            for (int c = 0; c < 2; c++) {
                float o = fmaxf(acc[m][c][j] + bcol[c], 0.f);
                float o2 = __shfl_xor(o, 1);  // partner col (lane^1): same row, col^1
                int col = w * 32 + c * 16 + lrow;
                if (write_out)
                    __builtin_nontemporal_store(o, out + (size_t)rowi * 128 + col);
                if (write_h && !(f & 1))
                    xs_out[(size_t)rowi * 64 + (col >> 1)] =
                        __floats2half2_rn(dvr * o, dvr * o2);
            }
        }
    }
}

// ---------------- launch ----------------

extern "C" void kernel_launch(void* const* d_in, const int* in_sizes, int n_in,
                              void* d_out, int out_size, void* d_ws, size_t ws_size,
                              hipStream_t stream) {
    const int* edge = (const int*)d_in[0];   // [2, E] int32
    const float* emb = (const float*)d_in[1];
    const float* Ws = (const float*)d_in[2]; // [L, D, D]
    const float* bs = (const float*)d_in[3]; // [L, D]
    float* out = (float*)d_out;

    const int n = N_NODES, e = N_EDGES;
    const int* row = edge;       // sources
    const int* col = edge + e;   // targets

    char* p = (char*)d_ws;
    _Float16* Ah = (_Float16*)p;              // 25.6 MB (hi plane)
    int* deg = (int*)p;                       // aliases Ah: build-phase only
    int* cur = deg + N_NODES;
    int* totals = cur + N_NODES;              // NSCAN chunk totals
    p += (size_t)n * D * 2;
    _Float16* Al = (_Float16*)p;
    p += (size_t)n * D * 2;                   // 25.6 MB (lo plane)
    __half2* xs = (__half2*)p;                // 25.6 MB (pre-scaled fp16 features)
    p += (size_t)n * D * 2;
    int* csr_src  = (int*)p;    p += (size_t)e * 4;           // 6.4 MB
    float* dinv   = (float*)p;  p += (size_t)n * 4;
    int* offsets  = (int*)p;    p += (size_t)(n + 1) * 4;
    _Float16* WhT = (_Float16*)p; p += (size_t)NLAYERS * D * D * 2;  // 98 KB
    _Float16* WlT = (_Float16*)p; p += (size_t)NLAYERS * D * D * 2;  // 98 KB

    // CSR build: global-atomic counting sort (R10: replaces the 6-kernel
    // bucket sort that had 13-128-block dispatches idling most of the GPU)
    zero_kernel<<<NSCAN, 256, 0, stream>>>(deg, n);
    deg_kernel<<<e / 256, 256, 0, stream>>>(col, deg);
    scan1_kernel<<<NSCAN, 256, 0, stream>>>(deg, offsets, totals, n);
    scan2_kernel<<<1, 512, 0, stream>>>(totals, NSCAN);
    scan3_kernel<<<NSCAN, 256, 0, stream>>>(deg, offsets, totals, cur, dinv, n, e);
    scatter2_kernel<<<e / 256, 256, 0, stream>>>(row, col, cur, csr_src);
    wsplit_kernel<<<dim3(128, NLAYERS), 128, 0, stream>>>(Ws, WhT, WlT);

    int n2 = n * 64;  // half2 count
    cast_kernel<<<(n2 + 255) / 256, 256, 0, stream>>>((const float2*)emb, dinv, xs, n2);

    const int half = n / 2;  // 50000
    for (int l = 0; l < NLAYERS; l++) {
        agg_kernel<<<half, 64, 0, stream>>>(xs, offsets, (unsigned*)Ah, (unsigned*)Al,
                                            dinv, csr_src, 0);
        agg_kernel<<<half, 64, 0, stream>>>(xs, offsets, (unsigned*)Ah, (unsigned*)Al,
                                            dinv, csr_src, half);
        gemm_mfma_kernel<<<n / 32, 256, 0, stream>>>(
            Ah, Al, WhT + (size_t)l * D * D, WlT + (size_t)l * D * D,
            bs + (size_t)l * D, out, xs, dinv,
            (l < NLAYERS - 1) ? 1 : 0, (l == NLAYERS - 1) ? 1 : 0);
    }
}

// Round 12
// 507.242 us; speedup vs baseline: 1.2351x; 1.2351x over previous
//
#include <hip/hip_runtime.h>
#include <hip/hip_fp16.h>
#include <cstdint>
#include <cstddef>

#define N_NODES 100000
#define N_EDGES 1600000
#define D 128
#define NLAYERS 3
#define NB 3125       // buckets of 32 nodes
#define NBLK_E 128    // edge-phase blocks
#define EPB 12500     // edges per block: 1600000/128
#define ENT_CAP 1024  // fill2 LDS entries; bucket max ~600 (22 sigma)

typedef float f2v __attribute__((ext_vector_type(2)));
typedef _Float16 f16x8 __attribute__((ext_vector_type(8)));
typedef float f32x4 __attribute__((ext_vector_type(4)));
typedef unsigned u32x4 __attribute__((ext_vector_type(4)));

// ---------------- CSR build: LDS-histogram counting sort ----------------
// R11 post-mortem: global-atomic CSR was +127us — scatter2 alone 122us with
// WRITE_SIZE 106MB for a 6.4MB array (random 4B writes to 64B lines shared
// across XCDs -> non-coherent L2 line ping-pong through HBM). The bucket
// sort exists precisely to localize CSR writes per block. Restored.

__global__ __launch_bounds__(512) void hist1_kernel(const int* __restrict__ col,
                                                    int* __restrict__ hmat) {
    __shared__ int hist[NB];
    int b = blockIdx.x, t = threadIdx.x;
    for (int j = t; j < NB; j += 512) hist[j] = 0;
    __syncthreads();
    int base = b * EPB;
    for (int i = t; i < EPB; i += 512) {
        int c = col[base + i];
        atomicAdd(&hist[c >> 5], 1);  // LDS atomic
    }
    __syncthreads();
    for (int j = t; j < NB; j += 512) hmat[b * NB + j] = hist[j];
}

__global__ void btot_kernel(const int* __restrict__ hmat, int* __restrict__ btot) {
    int j = blockIdx.x * 256 + threadIdx.x;
    if (j < NB) {
        int s = 0;
        for (int b = 0; b < NBLK_E; b++) s += hmat[b * NB + j];
        btot[j] = s;
    }
}

// Single-block exclusive scan over 3125 bucket totals -> bstart (+ sentinel).
__global__ void bscan_kernel(const int* __restrict__ btot, int* __restrict__ bstart, int nb, int e) {
    __shared__ int lsum[1024];
    int t = threadIdx.x;
    int vals[4];
    int v0 = 0;
#pragma unroll
    for (int j = 0; j < 4; j++) {
        int idx = t * 4 + j;
        int c = (idx < nb) ? btot[idx] : 0;
        vals[j] = c;
        v0 += c;
    }
    lsum[t] = v0;
    __syncthreads();
    for (int off = 1; off < 1024; off <<= 1) {
        int x = (t >= off) ? lsum[t - off] : 0;
        __syncthreads();
        lsum[t] += x;
        __syncthreads();
    }
    int base = lsum[t] - v0;  // exclusive
#pragma unroll
    for (int j = 0; j < 4; j++) {
        int idx = t * 4 + j;
        if (idx < nb) {
            bstart[idx] = base;
            base += vals[j];
        }
    }
    if (t == 0) bstart[nb] = e;
}

// Per-(block,bucket) start offsets: hoff[b][j] = bstart[j] + sum_{b'<b} hmat[b'][j]
__global__ void hoff_kernel(const int* __restrict__ hmat, const int* __restrict__ bstart,
                            int* __restrict__ hoff) {
    int j = blockIdx.x * 256 + threadIdx.x;
    if (j < NB) {
        int run = bstart[j];
        for (int b = 0; b < NBLK_E; b++) {
            hoff[b * NB + j] = run;
            run += hmat[b * NB + j];
        }
    }
}

// Scatter edges to exact bucket-sorted positions. LDS cursors, no global atomics.
__global__ __launch_bounds__(512) void scatter_kernel(const int* __restrict__ row,
                                                      const int* __restrict__ col,
                                                      const int* __restrict__ hoff,
                                                      unsigned* __restrict__ bucketbuf) {
    __shared__ int cur[NB];
    int b = blockIdx.x, t = threadIdx.x;
    for (int j = t; j < NB; j += 512) cur[j] = hoff[b * NB + j];
    __syncthreads();
    int base = b * EPB;
    for (int i = t; i < EPB; i += 512) {
        int r = row[base + i], c = col[base + i];
        int pos = atomicAdd(&cur[c >> 5], 1);  // LDS atomic
        bucketbuf[pos] = ((unsigned)r << 5) | (unsigned)(c & 31);
    }
}

// One block per bucket: LDS histogram of 32 local cols -> per-node offsets,
// dinv, and localized CSR scatter (contiguous ~2KB range, LDS cursors).
__global__ void fill2_kernel(const unsigned* __restrict__ bucketbuf, const int* __restrict__ bstart,
                             int* __restrict__ offsets, float* __restrict__ dinv,
                             int* __restrict__ src, int n, int e) {
    __shared__ unsigned ent[ENT_CAP];
    __shared__ int hist[32];
    __shared__ int cur[32];
    __shared__ int loff[32];
    int b = blockIdx.x, t = threadIdx.x;
    int s0 = bstart[b];
    int cnt = bstart[b + 1] - s0;
    if (cnt > ENT_CAP) cnt = ENT_CAP;
    if (t < 32) hist[t] = 0;
    __syncthreads();
    for (int i = t; i < cnt; i += 256) {
        unsigned v = bucketbuf[s0 + i];
        ent[i] = v;
        atomicAdd(&hist[v & 31], 1);
    }
    __syncthreads();
    if (t == 0) {
        int run = s0;
#pragma unroll
        for (int j = 0; j < 32; j++) {
            loff[j] = run;
            run += hist[j];
        }
    }
    __syncthreads();
    if (t < 32) {
        int node = b * 32 + t;
        int o = loff[t];
        offsets[node] = o;
        cur[t] = o;
        dinv[node] = rsqrtf((float)(hist[t] + 1));  // +1 self loop
    }
    if (b == 0 && t == 0) offsets[n] = e;
    __syncthreads();
    for (int i = t; i < cnt; i += 256) {
        unsigned v = ent[i];
        int pos = atomicAdd(&cur[v & 31], 1);
        src[pos] = (int)(v >> 5);
    }
}

// ---------------- per-layer kernels ----------------

// Cast + pre-scale: xs[v] = fp16(dinv[v] * emb[v]). Pre-scaling removes the
// per-edge dinv[src] gather + multiply from the agg inner loop.
__global__ void cast_kernel(const float2* __restrict__ in, const float* __restrict__ dinv,
                            __half2* __restrict__ out, int n2) {
    int i = blockIdx.x * 256 + threadIdx.x;
    if (i < n2) {
        float d = dinv[i >> 6];  // wave-uniform (64 half2 per node)
        float2 v = in[i];
        out[i] = __floats2half2_rn(d * v.x, d * v.y);
    }
}

// W pre-split for the hi/lo fp16 MFMA: WhT/WlT[l][col][k] (transposed,
// fragment-ready). w = wh + wl with wh=fp16(w), wl=fp16(w-wh): 22-bit
// combined mantissa -> GEMM error ~2^-20, far below the fp16-gather noise.
__global__ void wsplit_kernel(const float* __restrict__ W,
                              _Float16* __restrict__ Wh, _Float16* __restrict__ Wl) {
    int c = blockIdx.x, l = blockIdx.y, k = threadIdx.x;  // 128 threads
    float w = W[(size_t)l * 16384 + k * 128 + c];
    _Float16 h = (_Float16)w;
    float r = w - (float)h;
    Wh[(size_t)l * 16384 + c * 128 + k] = h;
    Wl[(size_t)l * 16384 + c * 128 + k] = (_Float16)r;
}

// UNFUSED aggregation (R5/R10-verified 61.5us structure, 8-deep MLP).
// One 64-thread block (=1 wave) per node; xs PRE-SCALED (dinv*x):
//   a[v] = dinv[v] * ( xs[v] + sum_e xs[src_e] ), fp32 accum.
// vbase: grid split into two 50K dispatches purely for rocprof visibility —
// the ~53us gemm must surface in the top-5 (it has hidden under 61us agg
// rows for 6 rounds; both gemm geometry theories failed without counters).
// Output written as hi/lo fp16 planes (Ah, Al), NT-stored.
__global__ void agg_kernel(const __half2* __restrict__ xs, const int* __restrict__ offs,
                           unsigned* __restrict__ Ah, unsigned* __restrict__ Al,
                           const float* __restrict__ dinv, const int* __restrict__ src,
                           int vbase) {
    int v = vbase + blockIdx.x;
    int f = threadIdx.x;  // 0..63
    float dv = dinv[v];
    float2 a0 = __half22float2(xs[(size_t)v * 64 + f]);  // self term (already scaled)
    float ax = a0.x;
    float ay = a0.y;
    int i = offs[v], s1 = offs[v + 1];
    for (; i + 7 < s1; i += 8) {
        int s[8];
#pragma unroll
        for (int j = 0; j < 8; j++) s[j] = src[i + j];
        float2 x[8];
#pragma unroll
        for (int j = 0; j < 8; j++) x[j] = __half22float2(xs[(size_t)s[j] * 64 + f]);
#pragma unroll
        for (int j = 0; j < 8; j++) {
            ax += x[j].x;
            ay += x[j].y;
        }
    }
    if (i < s1) {  // masked tail group
        int last = s1 - 1;
        int s[8];
        float m[8];
#pragma unroll
        for (int j = 0; j < 8; j++) {
            int idx = i + j;
            bool in = idx < s1;
            s[j] = src[in ? idx : last];
            m[j] = in ? 1.0f : 0.0f;
        }
        float2 x[8];
#pragma unroll
        for (int j = 0; j < 8; j++) x[j] = __half22float2(xs[(size_t)s[j] * 64 + f]);
#pragma unroll
        for (int j = 0; j < 8; j++) {
            ax += m[j] * x[j].x;
            ay += m[j] * x[j].y;
        }
    }
    float rx = dv * ax, ry = dv * ay;
    __half2 h2 = __floats2half2_rn(rx, ry);
    float2 hb = __half22float2(h2);
    __half2 l2 = __floats2half2_rn(rx - hb.x, ry - hb.y);
    __builtin_nontemporal_store(__builtin_bit_cast(unsigned, h2), Ah + (size_t)v * 64 + f);
    __builtin_nontemporal_store(__builtin_bit_cast(unsigned, l2), Al + (size_t)v * 64 + f);
}

// out[M x 128] = relu(A[M x 128] @ W[128 x 128] + bias) via hi/lo fp16 MFMA.
// BM=32, 3125 blocks, 17.4KB LDS, W-frags from global L2. UNCHANGED —
// measured ~53us/layer by budget subtraction vs a ~12us roofline; both
// BM=128 (R5) and BM=32 (R10) land at ~53, so the binding constraint is
// NOT block geometry. Diagnosis deferred to this round's counters (agg
// split makes gemm visible in top-5 for the first time).
__global__ __launch_bounds__(256, 6) void gemm_mfma_kernel(
    const _Float16* __restrict__ Ahp, const _Float16* __restrict__ Alp,
    const _Float16* __restrict__ Whp, const _Float16* __restrict__ Wlp,  // [col][k]
    const float* __restrict__ bias, float* __restrict__ out,
    __half2* __restrict__ xs_out, const float* __restrict__ dinv,
    int write_h, int write_out) {
    __shared__ _Float16 sA[2][32][136];  // [plane][row][16 kg * 8 + 8 pad] = 17.4 KB
    int t = threadIdx.x;
    int f = t & 63;   // lane
    int w = t >> 6;   // wave 0..3 -> cols w*32 .. w*32+31
    int row0 = blockIdx.x * 32;

    // ---- stage A tile: 1024 qwords (2 planes x 32 rows x 16), 4 per thread ----
    const u32x4* Aq[2] = {(const u32x4*)Ahp, (const u32x4*)Alp};
#pragma unroll
    for (int i = 0; i < 4; i++) {
        int qid = t + 256 * i;          // 0..1023, bijective over (p, r, k2)
        int p = qid >> 9;
        int rem = qid & 511;
        int r = rem >> 4;               // 0..31
        int k2 = rem & 15;              // 16B k-group
        u32x4 v = __builtin_nontemporal_load(&Aq[p][(size_t)(row0 + r) * 16 + k2]);
        *(u32x4*)&sA[p][r][k2 * 8] = v;
    }
    __syncthreads();

    // ---- MFMA: rows 0..31 (2 m-frags) x wave's 32 cols (2 col-frags) ----
    int lrow = f & 15, kg = f >> 4;
    f32x4 acc[2][2];  // [m][c]
#pragma unroll
    for (int m = 0; m < 2; m++)
#pragma unroll
        for (int c = 0; c < 2; c++) acc[m][c] = (f32x4){0.f, 0.f, 0.f, 0.f};

#pragma unroll
    for (int ks = 0; ks < 4; ks++) {
        int g = ks * 4 + kg;  // 8-element k-group index
        f16x8 a0h = *(const f16x8*)&sA[0][lrow][g * 8];
        f16x8 a0l = *(const f16x8*)&sA[1][lrow][g * 8];
        f16x8 a1h = *(const f16x8*)&sA[0][16 + lrow][g * 8];
        f16x8 a1l = *(const f16x8*)&sA[1][16 + lrow][g * 8];
#pragma unroll
        for (int c = 0; c < 2; c++) {
            int col = w * 32 + c * 16 + lrow;
            f16x8 bh = *(const f16x8*)&Whp[(size_t)col * 128 + g * 8];
            f16x8 bl = *(const f16x8*)&Wlp[(size_t)col * 128 + g * 8];
            acc[0][c] = __builtin_amdgcn_mfma_f32_16x16x32_f16(a0h, bh, acc[0][c], 0, 0, 0);
            acc[0][c] = __builtin_amdgcn_mfma_f32_16x16x32_f16(a0l, bh, acc[0][c], 0, 0, 0);
            acc[0][c] = __builtin_amdgcn_mfma_f32_16x16x32_f16(a0h, bl, acc[0][c], 0, 0, 0);
            acc[1][c] = __builtin_amdgcn_mfma_f32_16x16x32_f16(a1h, bh, acc[1][c], 0, 0, 0);
            acc[1][c] = __builtin_amdgcn_mfma_f32_16x16x32_f16(a1l, bh, acc[1][c], 0, 0, 0);
            acc[1][c] = __builtin_amdgcn_mfma_f32_16x16x32_f16(a1h, bl, acc[1][c], 0, 0, 0);
        }
    }

    // ---- epilogue: bias + relu; C/D frag: col=lane&15, row=(lane>>4)*4+reg ----
    float bcol[2];
    bcol[0] = bias[w * 32 + 0 * 16 + lrow];
    bcol[1] = bias[w * 32 + 1 * 16 + lrow];
#pragma unroll
    for (int m = 0; m < 2; m++) {
        int rbase = row0 + m * 16 + kg * 4;
#pragma unroll
        for (int j = 0; j < 4; j++) {
            int rowi = rbase + j;
            float dvr = write_h ? dinv[rowi] : 0.f;
#pragma unroll
            for (int c = 0; c < 2; c++) {
                float o = fmaxf(acc[m][c][j] + bcol[c], 0.f);
                float o2 = __shfl_xor(o, 1);  // partner col (lane^1): same row, col^1
                int col = w * 32 + c * 16 + lrow;
                if (write_out)
                    __builtin_nontemporal_store(o, out + (size_t)rowi * 128 + col);
                if (write_h && !(f & 1))
                    xs_out[(size_t)rowi * 64 + (col >> 1)] =
                        __floats2half2_rn(dvr * o, dvr * o2);
            }
        }
    }
}

// ---------------- launch ----------------

extern "C" void kernel_launch(void* const* d_in, const int* in_sizes, int n_in,
                              void* d_out, int out_size, void* d_ws, size_t ws_size,
                              hipStream_t stream) {
    const int* edge = (const int*)d_in[0];   // [2, E] int32
    const float* emb = (const float*)d_in[1];
    const float* Ws = (const float*)d_in[2]; // [L, D, D]
    const float* bs = (const float*)d_in[3]; // [L, D]
    float* out = (float*)d_out;

    const int n = N_NODES, e = N_EDGES;
    const int* row = edge;       // sources
    const int* col = edge + e;   // targets

    char* p = (char*)d_ws;
    _Float16* Ah = (_Float16*)p;
    int* hmat = (int*)p;                      // aliases Ah (dead until first agg)
    int* hoff = hmat + (size_t)NBLK_E * NB;
    p += (size_t)n * D * 2;                   // 25.6 MB  (hi plane)
    _Float16* Al = (_Float16*)p;
    p += (size_t)n * D * 2;                   // 25.6 MB  (lo plane)
    __half2* xs = (__half2*)p;                // 25.6 MB (pre-scaled fp16 features)
    unsigned* bucketbuf = (unsigned*)p;       // aliases xs: dead before cast runs
    p += (size_t)n * D * 2;
    int* csr_src  = (int*)p;    p += (size_t)e * 4;           // 6.4 MB
    float* dinv   = (float*)p;  p += (size_t)n * 4;
    int* offsets  = (int*)p;    p += (size_t)(n + 1) * 4;
    int* btot     = (int*)p;    p += (size_t)NB * 4;
    int* bstart   = (int*)p;    p += (size_t)(NB + 1) * 4;
    _Float16* WhT = (_Float16*)p; p += (size_t)NLAYERS * D * D * 2;  // 98 KB
    _Float16* WlT = (_Float16*)p; p += (size_t)NLAYERS * D * D * 2;  // 98 KB

    hist1_kernel<<<NBLK_E, 512, 0, stream>>>(col, hmat);
    btot_kernel<<<(NB + 255) / 256, 256, 0, stream>>>(hmat, btot);
    bscan_kernel<<<1, 1024, 0, stream>>>(btot, bstart, NB, e);
    hoff_kernel<<<(NB + 255) / 256, 256, 0, stream>>>(hmat, bstart, hoff);
    scatter_kernel<<<NBLK_E, 512, 0, stream>>>(row, col, hoff, bucketbuf);
    fill2_kernel<<<NB, 256, 0, stream>>>(bucketbuf, bstart, offsets, dinv, csr_src, n, e);
    wsplit_kernel<<<dim3(128, NLAYERS), 128, 0, stream>>>(Ws, WhT, WlT);

    int n2 = n * 64;  // half2 count
    cast_kernel<<<(n2 + 255) / 256, 256, 0, stream>>>((const float2*)emb, dinv, xs, n2);

    const int half = n / 2;  // 50000
    for (int l = 0; l < NLAYERS; l++) {
        agg_kernel<<<half, 64, 0, stream>>>(xs, offsets, (unsigned*)Ah, (unsigned*)Al,
                                            dinv, csr_src, 0);
        agg_kernel<<<half, 64, 0, stream>>>(xs, offsets, (unsigned*)Ah, (unsigned*)Al,
                                            dinv, csr_src, half);
        gemm_mfma_kernel<<<n / 32, 256, 0, stream>>>(
            Ah, Al, WhT + (size_t)l * D * D, WlT + (size_t)l * D * D,
            bs + (size_t)l * D, out, xs, dinv,
            (l < NLAYERS - 1) ? 1 : 0, (l == NLAYERS - 1) ? 1 : 0);
    }
}

// Round 15
// 497.940 us; speedup vs baseline: 1.2582x; 1.0187x over previous
//
#include <hip/hip_runtime.h>
#include <hip/hip_fp16.h>
#include <cstdint>
#include <cstddef>

#define N_NODES 100000
#define N_EDGES 1600000
#define D 128
#define NLAYERS 3
#define NB 3125       // buckets of 32 nodes
#define NBLK_E 128    // edge-phase blocks
#define EPB 12500     // edges per block: 1600000/128
#define ENT_CAP 1024  // fill2 LDS entries; bucket max ~600 (22 sigma)

typedef float f2v __attribute__((ext_vector_type(2)));
typedef _Float16 f16x8 __attribute__((ext_vector_type(8)));
typedef float f32x4 __attribute__((ext_vector_type(4)));
typedef unsigned u32x4 __attribute__((ext_vector_type(4)));

// ---------------- CSR build: LDS-histogram counting sort ----------------
// R11: global-atomic CSR was +127us (scatter WRITE amplification 17x from
// cross-XCD line ping-pong). Bucket sort localizes CSR writes per block.

__global__ __launch_bounds__(512) void hist1_kernel(const int* __restrict__ col,
                                                    int* __restrict__ hmat) {
    __shared__ int hist[NB];
    int b = blockIdx.x, t = threadIdx.x;
    for (int j = t; j < NB; j += 512) hist[j] = 0;
    __syncthreads();
    int base = b * EPB;
    for (int i = t; i < EPB; i += 512) {
        int c = col[base + i];
        atomicAdd(&hist[c >> 5], 1);  // LDS atomic
    }
    __syncthreads();
    for (int j = t; j < NB; j += 512) hmat[b * NB + j] = hist[j];
}

__global__ void btot_kernel(const int* __restrict__ hmat, int* __restrict__ btot) {
    int j = blockIdx.x * 256 + threadIdx.x;
    if (j < NB) {
        int s = 0;
        for (int b = 0; b < NBLK_E; b++) s += hmat[b * NB + j];
        btot[j] = s;
    }
}

// Single-block exclusive scan over 3125 bucket totals -> bstart (+ sentinel).
__global__ void bscan_kernel(const int* __restrict__ btot, int* __restrict__ bstart, int nb, int e) {
    __shared__ int lsum[1024];
    int t = threadIdx.x;
    int vals[4];
    int v0 = 0;
#pragma unroll
    for (int j = 0; j < 4; j++) {
        int idx = t * 4 + j;
        int c = (idx < nb) ? btot[idx] : 0;
        vals[j] = c;
        v0 += c;
    }
    lsum[t] = v0;
    __syncthreads();
    for (int off = 1; off < 1024; off <<= 1) {
        int x = (t >= off) ? lsum[t - off] : 0;
        __syncthreads();
        lsum[t] += x;
        __syncthreads();
    }
    int base = lsum[t] - v0;  // exclusive
#pragma unroll
    for (int j = 0; j < 4; j++) {
        int idx = t * 4 + j;
        if (idx < nb) {
            bstart[idx] = base;
            base += vals[j];
        }
    }
    if (t == 0) bstart[nb] = e;
}

// Per-(block,bucket) start offsets: hoff[b][j] = bstart[j] + sum_{b'<b} hmat[b'][j]
__global__ void hoff_kernel(const int* __restrict__ hmat, const int* __restrict__ bstart,
                            int* __restrict__ hoff) {
    int j = blockIdx.x * 256 + threadIdx.x;
    if (j < NB) {
        int run = bstart[j];
        for (int b = 0; b < NBLK_E; b++) {
            hoff[b * NB + j] = run;
            run += hmat[b * NB + j];
        }
    }
}

// Scatter edges to exact bucket-sorted positions. LDS cursors, no global atomics.
__global__ __launch_bounds__(512) void scatter_kernel(const int* __restrict__ row,
                                                      const int* __restrict__ col,
                                                      const int* __restrict__ hoff,
                                                      unsigned* __restrict__ bucketbuf) {
    __shared__ int cur[NB];
    int b = blockIdx.x, t = threadIdx.x;
    for (int j = t; j < NB; j += 512) cur[j] = hoff[b * NB + j];
    __syncthreads();
    int base = b * EPB;
    for (int i = t; i < EPB; i += 512) {
        int r = row[base + i], c = col[base + i];
        int pos = atomicAdd(&cur[c >> 5], 1);  // LDS atomic
        bucketbuf[pos] = ((unsigned)r << 5) | (unsigned)(c & 31);
    }
}

// One block per bucket: LDS histogram of 32 local cols -> per-node offsets,
// dinv, and localized CSR scatter (contiguous ~2KB range, LDS cursors).
__global__ void fill2_kernel(const unsigned* __restrict__ bucketbuf, const int* __restrict__ bstart,
                             int* __restrict__ offsets, float* __restrict__ dinv,
                             int* __restrict__ src, int n, int e) {
    __shared__ unsigned ent[ENT_CAP];
    __shared__ int hist[32];
    __shared__ int cur[32];
    __shared__ int loff[32];
    int b = blockIdx.x, t = threadIdx.x;
    int s0 = bstart[b];
    int cnt = bstart[b + 1] - s0;
    if (cnt > ENT_CAP) cnt = ENT_CAP;
    if (t < 32) hist[t] = 0;
    __syncthreads();
    for (int i = t; i < cnt; i += 256) {
        unsigned v = bucketbuf[s0 + i];
        ent[i] = v;
        atomicAdd(&hist[v & 31], 1);
    }
    __syncthreads();
    if (t == 0) {
        int run = s0;
#pragma unroll
        for (int j = 0; j < 32; j++) {
            loff[j] = run;
            run += hist[j];
        }
    }
    __syncthreads();
    if (t < 32) {
        int node = b * 32 + t;
        int o = loff[t];
        offsets[node] = o;
        cur[t] = o;
        dinv[node] = rsqrtf((float)(hist[t] + 1));  // +1 self loop
    }
    if (b == 0 && t == 0) offsets[n] = e;
    __syncthreads();
    for (int i = t; i < cnt; i += 256) {
        unsigned v = ent[i];
        int pos = atomicAdd(&cur[v & 31], 1);
        src[pos] = (int)(v >> 5);
    }
}

// ---------------- per-layer kernels ----------------

// Cast + pre-scale: xs[v] = fp16(dinv[v] * emb[v]). Pre-scaling removes the
// per-edge dinv[src] gather + multiply from the agg inner loop.
__global__ void cast_kernel(const float2* __restrict__ in, const float* __restrict__ dinv,
                            __half2* __restrict__ out, int n2) {
    int i = blockIdx.x * 256 + threadIdx.x;
    if (i < n2) {
        float d = dinv[i >> 6];  // wave-uniform (64 half2 per node)
        float2 v = in[i];
        out[i] = __floats2half2_rn(d * v.x, d * v.y);
    }
}

// W pre-split for the hi/lo fp16 MFMA: WhT/WlT[l][col][k] (transposed,
// fragment-ready). w = wh + wl with wh=fp16(w), wl=fp16(w-wh): 22-bit
// combined mantissa -> GEMM error ~2^-20, far below the fp16-gather noise.
__global__ void wsplit_kernel(const float* __restrict__ W,
                              _Float16* __restrict__ Wh, _Float16* __restrict__ Wl) {
    int c = blockIdx.x, l = blockIdx.y, k = threadIdx.x;  // 128 threads
    float w = W[(size_t)l * 16384 + k * 128 + c];
    _Float16 h = (_Float16)w;
    float r = w - (float)h;
    Wh[(size_t)l * 16384 + c * 128 + k] = h;
    Wl[(size_t)l * 16384 + c * 128 + k] = (_Float16)r;
}

// UNFUSED aggregation (R5/R10-verified 61.5us structure, 8-deep MLP).
// R12 change: Ah/Al stores are now REGULAR (were nontemporal). R12 counters
// showed the gemm latency-bound on the A round-trip: NT stores bypass L2 ->
// planes live only in HBM -> gemm's NT loads pay ~900cy each with all pipes
// <9% busy. Regular stores let the 51.2MB intermediate live in L2/L3
// (256MB L3 >> 77MB total working set); gemm then fills from L3.
__global__ void agg_kernel(const __half2* __restrict__ xs, const int* __restrict__ offs,
                           unsigned* __restrict__ Ah, unsigned* __restrict__ Al,
                           const float* __restrict__ dinv, const int* __restrict__ src,
                           int vbase) {
    int v = vbase + blockIdx.x;
    int f = threadIdx.x;  // 0..63
    float dv = dinv[v];
    float2 a0 = __half22float2(xs[(size_t)v * 64 + f]);  // self term (already scaled)
    float ax = a0.x;
    float ay = a0.y;
    int i = offs[v], s1 = offs[v + 1];
    for (; i + 7 < s1; i += 8) {
        int s[8];
#pragma unroll
        for (int j = 0; j < 8; j++) s[j] = src[i + j];
        float2 x[8];
#pragma unroll
        for (int j = 0; j < 8; j++) x[j] = __half22float2(xs[(size_t)s[j] * 64 + f]);
#pragma unroll
        for (int j = 0; j < 8; j++) {
            ax += x[j].x;
            ay += x[j].y;
        }
    }
    if (i < s1) {  // masked tail group
        int last = s1 - 1;
        int s[8];
        float m[8];
#pragma unroll
        for (int j = 0; j < 8; j++) {
            int idx = i + j;
            bool in = idx < s1;
            s[j] = src[in ? idx : last];
            m[j] = in ? 1.0f : 0.0f;
        }
        float2 x[8];
#pragma unroll
        for (int j = 0; j < 8; j++) x[j] = __half22float2(xs[(size_t)s[j] * 64 + f]);
#pragma unroll
        for (int j = 0; j < 8; j++) {
            ax += m[j] * x[j].x;
            ay += m[j] * x[j].y;
        }
    }
    float rx = dv * ax, ry = dv * ay;
    __half2 h2 = __floats2half2_rn(rx, ry);
    float2 hb = __half22float2(h2);
    __half2 l2 = __floats2half2_rn(rx - hb.x, ry - hb.y);
    Ah[(size_t)v * 64 + f] = __builtin_bit_cast(unsigned, h2);   // regular: L2/L3-resident
    Al[(size_t)v * 64 + f] = __builtin_bit_cast(unsigned, l2);
}

// out[M x 128] = relu(A[M x 128] @ W[128 x 128] + bias) via hi/lo fp16 MFMA.
// BM=32, 3125 blocks, 17.4KB LDS, W-frags from global L2.
// R12 change: A-tile staging loads are REGULAR (were nontemporal) — pairs
// with agg's regular stores so the A planes are served from L3 (~200-300cy)
// instead of HBM (~900cy). R12 counters: 47.7us, MfmaUtil 7%, VALUBusy 9%,
// 2.0 TB/s — pure latency-bound on the HBM round-trip, NOT geometry (BM=128
// and BM=32 identical) and NOT LDS (conflicts negligible).
__global__ __launch_bounds__(256, 6) void gemm_mfma_kernel(
    const _Float16* __restrict__ Ahp, const _Float16* __restrict__ Alp,
    const _Float16* __restrict__ Whp, const _Float16* __restrict__ Wlp,  // [col][k]
    const float* __restrict__ bias, float* __restrict__ out,
    __half2* __restrict__ xs_out, const float* __restrict__ dinv,
    int write_h, int write_out) {
    __shared__ _Float16 sA[2][32][136];  // [plane][row][16 kg * 8 + 8 pad] = 17.4 KB
    int t = threadIdx.x;
    int f = t & 63;   // lane
    int w = t >> 6;   // wave 0..3 -> cols w*32 .. w*32+31
    int row0 = blockIdx.x * 32;

    // ---- stage A tile: 1024 qwords (2 planes x 32 rows x 16), 4 per thread ----
    const u32x4* Aq[2] = {(const u32x4*)Ahp, (const u32x4*)Alp};
#pragma unroll
    for (int i = 0; i < 4; i++) {
        int qid = t + 256 * i;          // 0..1023, bijective over (p, r, k2)
        int p = qid >> 9;
        int rem = qid & 511;
        int r = rem >> 4;               // 0..31
        int k2 = rem & 15;              // 16B k-group
        u32x4 v = Aq[p][(size_t)(row0 + r) * 16 + k2];   // regular load: L3 fill
        *(u32x4*)&sA[p][r][k2 * 8] = v;
    }
    __syncthreads();

    // ---- MFMA: rows 0..31 (2 m-frags) x wave's 32 cols (2 col-frags) ----
    int lrow = f & 15, kg = f >> 4;
    f32x4 acc[2][2];  // [m][c]
#pragma unroll
    for (int m = 0; m < 2; m++)
#pragma unroll
        for (int c = 0; c < 2; c++) acc[m][c] = (f32x4){0.f, 0.f, 0.f, 0.f};

#pragma unroll
    for (int ks = 0; ks < 4; ks++) {
        int g = ks * 4 + kg;  // 8-element k-group index
        f16x8 a0h = *(const f16x8*)&sA[0][lrow][g * 8];
        f16x8 a0l = *(const f16x8*)&sA[1][lrow][g * 8];
        f16x8 a1h = *(const f16x8*)&sA[0][16 + lrow][g * 8];
        f16x8 a1l = *(const f16x8*)&sA[1][16 + lrow][g * 8];
#pragma unroll
        for (int c = 0; c < 2; c++) {
            int col = w * 32 + c * 16 + lrow;
            f16x8 bh = *(const f16x8*)&Whp[(size_t)col * 128 + g * 8];
            f16x8 bl = *(const f16x8*)&Wlp[(size_t)col * 128 + g * 8];
            acc[0][c] = __builtin_amdgcn_mfma_f32_16x16x32_f16(a0h, bh, acc[0][c], 0, 0, 0);
            acc[0][c] = __builtin_amdgcn_mfma_f32_16x16x32_f16(a0l, bh, acc[0][c], 0, 0, 0);
            acc[0][c] = __builtin_amdgcn_mfma_f32_16x16x32_f16(a0h, bl, acc[0][c], 0, 0, 0);
            acc[1][c] = __builtin_amdgcn_mfma_f32_16x16x32_f16(a1h, bh, acc[1][c], 0, 0, 0);
            acc[1][c] = __builtin_amdgcn_mfma_f32_16x16x32_f16(a1l, bh, acc[1][c], 0, 0, 0);
            acc[1][c] = __builtin_amdgcn_mfma_f32_16x16x32_f16(a1h, bl, acc[1][c], 0, 0, 0);
        }
    }

    // ---- epilogue: bias + relu; C/D frag: col=lane&15, row=(lane>>4)*4+reg ----
    float bcol[2];
    bcol[0] = bias[w * 32 + 0 * 16 + lrow];
    bcol[1] = bias[w * 32 + 1 * 16 + lrow];
#pragma unroll
    for (int m = 0; m < 2; m++) {
        int rbase = row0 + m * 16 + kg * 4;
#pragma unroll
        for (int j = 0; j < 4; j++) {
            int rowi = rbase + j;
            float dvr = write_h ? dinv[rowi] : 0.f;
#pragma unroll
            for (int c = 0; c < 2; c++) {
                float o = fmaxf(acc[m][c][j] + bcol[c], 0.f);
                float o2 = __shfl_xor(o, 1);  // partner col (lane^1): same row, col^1
                int col = w * 32 + c * 16 + lrow;
                if (write_out)
                    __builtin_nontemporal_store(o, out + (size_t)rowi * 128 + col);
                if (write_h && !(f & 1))
                    xs_out[(size_t)rowi * 64 + (col >> 1)] =
                        __floats2half2_rn(dvr * o, dvr * o2);
            }
        }
    }
}

// ---------------- launch ----------------

extern "C" void kernel_launch(void* const* d_in, const int* in_sizes, int n_in,
                              void* d_out, int out_size, void* d_ws, size_t ws_size,
                              hipStream_t stream) {
    const int* edge = (const int*)d_in[0];   // [2, E] int32
    const float* emb = (const float*)d_in[1];
    const float* Ws = (const float*)d_in[2]; // [L, D, D]
    const float* bs = (const float*)d_in[3]; // [L, D]
    float* out = (float*)d_out;

    const int n = N_NODES, e = N_EDGES;
    const int* row = edge;       // sources
    const int* col = edge + e;   // targets

    char* p = (char*)d_ws;
    _Float16* Ah = (_Float16*)p;
    int* hmat = (int*)p;                      // aliases Ah (dead until first agg)
    int* hoff = hmat + (size_t)NBLK_E * NB;
    p += (size_t)n * D * 2;                   // 25.6 MB  (hi plane)
    _Float16* Al = (_Float16*)p;
    p += (size_t)n * D * 2;                   // 25.6 MB  (lo plane)
    __half2* xs = (__half2*)p;                // 25.6 MB (pre-scaled fp16 features)
    unsigned* bucketbuf = (unsigned*)p;       // aliases xs: dead before cast runs
    p += (size_t)n * D * 2;
    int* csr_src  = (int*)p;    p += (size_t)e * 4;           // 6.4 MB
    float* dinv   = (float*)p;  p += (size_t)n * 4;
    int* offsets  = (int*)p;    p += (size_t)(n + 1) * 4;
    int* btot     = (int*)p;    p += (size_t)NB * 4;
    int* bstart   = (int*)p;    p += (size_t)(NB + 1) * 4;
    _Float16* WhT = (_Float16*)p; p += (size_t)NLAYERS * D * D * 2;  // 98 KB
    _Float16* WlT = (_Float16*)p; p += (size_t)NLAYERS * D * D * 2;  // 98 KB

    hist1_kernel<<<NBLK_E, 512, 0, stream>>>(col, hmat);
    btot_kernel<<<(NB + 255) / 256, 256, 0, stream>>>(hmat, btot);
    bscan_kernel<<<1, 1024, 0, stream>>>(btot, bstart, NB, e);
    hoff_kernel<<<(NB + 255) / 256, 256, 0, stream>>>(hmat, bstart, hoff);
    scatter_kernel<<<NBLK_E, 512, 0, stream>>>(row, col, hoff, bucketbuf);
    fill2_kernel<<<NB, 256, 0, stream>>>(bucketbuf, bstart, offsets, dinv, csr_src, n, e);
    wsplit_kernel<<<dim3(128, NLAYERS), 128, 0, stream>>>(Ws, WhT, WlT);

    int n2 = n * 64;  // half2 count
    cast_kernel<<<(n2 + 255) / 256, 256, 0, stream>>>((const float2*)emb, dinv, xs, n2);

    const int half = n / 2;  // 50000
    for (int l = 0; l < NLAYERS; l++) {
        agg_kernel<<<half, 64, 0, stream>>>(xs, offsets, (unsigned*)Ah, (unsigned*)Al,
                                            dinv, csr_src, 0);
        agg_kernel<<<half, 64, 0, stream>>>(xs, offsets, (unsigned*)Ah, (unsigned*)Al,
                                            dinv, csr_src, half);
        gemm_mfma_kernel<<<n / 32, 256, 0, stream>>>(
            Ah, Al, WhT + (size_t)l * D * D, WlT + (size_t)l * D * D,
            bs + (size_t)l * D, out, xs, dinv,
            (l < NLAYERS - 1) ? 1 : 0, (l == NLAYERS - 1) ? 1 : 0);
    }
}

// Round 16
// 477.232 us; speedup vs baseline: 1.3128x; 1.0434x over previous
//
#include <hip/hip_runtime.h>
#include <hip/hip_fp16.h>
#include <cstdint>
#include <cstddef>

#define N_NODES 100000
#define N_EDGES 1600000
#define D 128
#define NLAYERS 3
#define NB 3125       // buckets of 32 nodes
#define NBLK_E 128    // edge-phase blocks
#define EPB 12500     // edges per block: 1600000/128
#define ENT_CAP 1024  // fill2 LDS entries; bucket max ~600 (22 sigma)

typedef float f2v __attribute__((ext_vector_type(2)));
typedef _Float16 f16x8 __attribute__((ext_vector_type(8)));
typedef float f32x4 __attribute__((ext_vector_type(4)));
typedef unsigned u32x4 __attribute__((ext_vector_type(4)));

// ---------------- CSR build: LDS-histogram counting sort ----------------
// R11: global-atomic CSR was +127us (scatter WRITE amplification 17x from
// cross-XCD line ping-pong). Bucket sort localizes CSR writes per block.
// R15 counters: scatter 45.7us at 8.5% occupancy (128-block grid) — CSR
// parallelism is the NEXT target, after this round's precision experiment.

__global__ __launch_bounds__(512) void hist1_kernel(const int* __restrict__ col,
                                                    int* __restrict__ hmat) {
    __shared__ int hist[NB];
    int b = blockIdx.x, t = threadIdx.x;
    for (int j = t; j < NB; j += 512) hist[j] = 0;
    __syncthreads();
    int base = b * EPB;
    for (int i = t; i < EPB; i += 512) {
        int c = col[base + i];
        atomicAdd(&hist[c >> 5], 1);  // LDS atomic
    }
    __syncthreads();
    for (int j = t; j < NB; j += 512) hmat[b * NB + j] = hist[j];
}

__global__ void btot_kernel(const int* __restrict__ hmat, int* __restrict__ btot) {
    int j = blockIdx.x * 256 + threadIdx.x;
    if (j < NB) {
        int s = 0;
        for (int b = 0; b < NBLK_E; b++) s += hmat[b * NB + j];
        btot[j] = s;
    }
}

// Single-block exclusive scan over 3125 bucket totals -> bstart (+ sentinel).
__global__ void bscan_kernel(const int* __restrict__ btot, int* __restrict__ bstart, int nb, int e) {
    __shared__ int lsum[1024];
    int t = threadIdx.x;
    int vals[4];
    int v0 = 0;
#pragma unroll
    for (int j = 0; j < 4; j++) {
        int idx = t * 4 + j;
        int c = (idx < nb) ? btot[idx] : 0;
        vals[j] = c;
        v0 += c;
    }
    lsum[t] = v0;
    __syncthreads();
    for (int off = 1; off < 1024; off <<= 1) {
        int x = (t >= off) ? lsum[t - off] : 0;
        __syncthreads();
        lsum[t] += x;
        __syncthreads();
    }
    int base = lsum[t] - v0;  // exclusive
#pragma unroll
    for (int j = 0; j < 4; j++) {
        int idx = t * 4 + j;
        if (idx < nb) {
            bstart[idx] = base;
            base += vals[j];
        }
    }
    if (t == 0) bstart[nb] = e;
}

// Per-(block,bucket) start offsets: hoff[b][j] = bstart[j] + sum_{b'<b} hmat[b'][j]
__global__ void hoff_kernel(const int* __restrict__ hmat, const int* __restrict__ bstart,
                            int* __restrict__ hoff) {
    int j = blockIdx.x * 256 + threadIdx.x;
    if (j < NB) {
        int run = bstart[j];
        for (int b = 0; b < NBLK_E; b++) {
            hoff[b * NB + j] = run;
            run += hmat[b * NB + j];
        }
    }
}

// Scatter edges to exact bucket-sorted positions. LDS cursors, no global atomics.
__global__ __launch_bounds__(512) void scatter_kernel(const int* __restrict__ row,
                                                      const int* __restrict__ col,
                                                      const int* __restrict__ hoff,
                                                      unsigned* __restrict__ bucketbuf) {
    __shared__ int cur[NB];
    int b = blockIdx.x, t = threadIdx.x;
    for (int j = t; j < NB; j += 512) cur[j] = hoff[b * NB + j];
    __syncthreads();
    int base = b * EPB;
    for (int i = t; i < EPB; i += 512) {
        int r = row[base + i], c = col[base + i];
        int pos = atomicAdd(&cur[c >> 5], 1);  // LDS atomic
        bucketbuf[pos] = ((unsigned)r << 5) | (unsigned)(c & 31);
    }
}

// One block per bucket: LDS histogram of 32 local cols -> per-node offsets,
// dinv, and localized CSR scatter (contiguous ~2KB range, LDS cursors).
__global__ void fill2_kernel(const unsigned* __restrict__ bucketbuf, const int* __restrict__ bstart,
                             int* __restrict__ offsets, float* __restrict__ dinv,
                             int* __restrict__ src, int n, int e) {
    __shared__ unsigned ent[ENT_CAP];
    __shared__ int hist[32];
    __shared__ int cur[32];
    __shared__ int loff[32];
    int b = blockIdx.x, t = threadIdx.x;
    int s0 = bstart[b];
    int cnt = bstart[b + 1] - s0;
    if (cnt > ENT_CAP) cnt = ENT_CAP;
    if (t < 32) hist[t] = 0;
    __syncthreads();
    for (int i = t; i < cnt; i += 256) {
        unsigned v = bucketbuf[s0 + i];
        ent[i] = v;
        atomicAdd(&hist[v & 31], 1);
    }
    __syncthreads();
    if (t == 0) {
        int run = s0;
#pragma unroll
        for (int j = 0; j < 32; j++) {
            loff[j] = run;
            run += hist[j];
        }
    }
    __syncthreads();
    if (t < 32) {
        int node = b * 32 + t;
        int o = loff[t];
        offsets[node] = o;
        cur[t] = o;
        dinv[node] = rsqrtf((float)(hist[t] + 1));  // +1 self loop
    }
    if (b == 0 && t == 0) offsets[n] = e;
    __syncthreads();
    for (int i = t; i < cnt; i += 256) {
        unsigned v = ent[i];
        int pos = atomicAdd(&cur[v & 31], 1);
        src[pos] = (int)(v >> 5);
    }
}

// ---------------- per-layer kernels ----------------

// Cast + pre-scale: xs[v] = fp16(dinv[v] * emb[v]). Pre-scaling removes the
// per-edge dinv[src] gather + multiply from the agg inner loop.
__global__ void cast_kernel(const float2* __restrict__ in, const float* __restrict__ dinv,
                            __half2* __restrict__ out, int n2) {
    int i = blockIdx.x * 256 + threadIdx.x;
    if (i < n2) {
        float d = dinv[i >> 6];  // wave-uniform (64 half2 per node)
        float2 v = in[i];
        out[i] = __floats2half2_rn(d * v.x, d * v.y);
    }
}

// W pre-split for the hi/lo fp16 MFMA: WhT/WlT[l][col][k] (transposed,
// fragment-ready). w = wh + wl, wh=fp16(w), wl=fp16(w-wh). W stays hi/lo
// (L2-resident, costs one extra MFMA only); the A-side lo plane is DROPPED
// as of R15 (see agg_kernel note).
__global__ void wsplit_kernel(const float* __restrict__ W,
                              _Float16* __restrict__ Wh, _Float16* __restrict__ Wl) {
    int c = blockIdx.x, l = blockIdx.y, k = threadIdx.x;  // 128 threads
    float w = W[(size_t)l * 16384 + k * 128 + c];
    _Float16 h = (_Float16)w;
    float r = w - (float)h;
    Wh[(size_t)l * 16384 + c * 128 + k] = h;
    Wl[(size_t)l * 16384 + c * 128 + k] = (_Float16)r;
}

// UNFUSED aggregation (R5/R10-verified 61.5us structure, 8-deep MLP).
// R15 change: the Al (lo-residual) plane is DROPPED — A is written as plain
// fp16. Error budget: absmax has been pinned at 2^-10 (xs-fp16 gather noise)
// for 10 rounds; fp16-A adds ~|a|*2^-11 per element -> ~4e-4/layer through
// the dot product, ~1.2e-3 worst over 3 layers -> predicted absmax ~2e-3 <
// 3.67e-3 threshold. Payoff: halves agg write traffic AND gemm A-read
// traffic (the two biggest budget items share the cost of this plane).
__global__ void agg_kernel(const __half2* __restrict__ xs, const int* __restrict__ offs,
                           unsigned* __restrict__ Ah,
                           const float* __restrict__ dinv, const int* __restrict__ src,
                           int vbase) {
    int v = vbase + blockIdx.x;
    int f = threadIdx.x;  // 0..63
    float dv = dinv[v];
    float2 a0 = __half22float2(xs[(size_t)v * 64 + f]);  // self term (already scaled)
    float ax = a0.x;
    float ay = a0.y;
    int i = offs[v], s1 = offs[v + 1];
    for (; i + 7 < s1; i += 8) {
        int s[8];
#pragma unroll
        for (int j = 0; j < 8; j++) s[j] = src[i + j];
        float2 x[8];
#pragma unroll
        for (int j = 0; j < 8; j++) x[j] = __half22float2(xs[(size_t)s[j] * 64 + f]);
#pragma unroll
        for (int j = 0; j < 8; j++) {
            ax += x[j].x;
            ay += x[j].y;
        }
    }
    if (i < s1) {  // masked tail group
        int last = s1 - 1;
        int s[8];
        float m[8];
#pragma unroll
        for (int j = 0; j < 8; j++) {
            int idx = i + j;
            bool in = idx < s1;
            s[j] = src[in ? idx : last];
            m[j] = in ? 1.0f : 0.0f;
        }
        float2 x[8];
#pragma unroll
        for (int j = 0; j < 8; j++) x[j] = __half22float2(xs[(size_t)s[j] * 64 + f]);
#pragma unroll
        for (int j = 0; j < 8; j++) {
            ax += m[j] * x[j].x;
            ay += m[j] * x[j].y;
        }
    }
    float rx = dv * ax, ry = dv * ay;
    __half2 h2 = __floats2half2_rn(rx, ry);
    Ah[(size_t)v * 64 + f] = __builtin_bit_cast(unsigned, h2);   // regular: L2/L3-resident
}

// out[M x 128] = relu(A[M x 128] @ W[128 x 128] + bias) via fp16 MFMA.
// BM=32, 3125 blocks. R15: single A plane (fp16), W still hi/lo:
//   h = a16 . wh + a16 . wl   (W at ~22-bit precision, A at fp16)
// LDS halves to 8.7KB, A-staging halves (2 qwords/thread), MFMA 48->32.
// R12 lesson kept: regular (non-NT) loads/stores on the A path so the
// intermediate stays L2/L3-resident.
__global__ __launch_bounds__(256, 6) void gemm_mfma_kernel(
    const _Float16* __restrict__ Ahp,
    const _Float16* __restrict__ Whp, const _Float16* __restrict__ Wlp,  // [col][k]
    const float* __restrict__ bias, float* __restrict__ out,
    __half2* __restrict__ xs_out, const float* __restrict__ dinv,
    int write_h, int write_out) {
    __shared__ _Float16 sA[32][136];  // [row][16 kg * 8 + 8 pad] = 8.7 KB
    int t = threadIdx.x;
    int f = t & 63;   // lane
    int w = t >> 6;   // wave 0..3 -> cols w*32 .. w*32+31
    int row0 = blockIdx.x * 32;

    // ---- stage A tile: 512 qwords (32 rows x 16), 2 per thread ----
    const u32x4* Aq = (const u32x4*)Ahp;
#pragma unroll
    for (int i = 0; i < 2; i++) {
        int qid = t + 256 * i;          // 0..511, bijective over (r, k2)
        int r = qid >> 4;               // 0..31
        int k2 = qid & 15;              // 16B k-group
        u32x4 v = Aq[(size_t)(row0 + r) * 16 + k2];   // regular load: L2/L3 fill
        *(u32x4*)&sA[r][k2 * 8] = v;
    }
    __syncthreads();

    // ---- MFMA: rows 0..31 (2 m-frags) x wave's 32 cols (2 col-frags) ----
    int lrow = f & 15, kg = f >> 4;
    f32x4 acc[2][2];  // [m][c]
#pragma unroll
    for (int m = 0; m < 2; m++)
#pragma unroll
        for (int c = 0; c < 2; c++) acc[m][c] = (f32x4){0.f, 0.f, 0.f, 0.f};

#pragma unroll
    for (int ks = 0; ks < 4; ks++) {
        int g = ks * 4 + kg;  // 8-element k-group index
        f16x8 a0 = *(const f16x8*)&sA[lrow][g * 8];
        f16x8 a1 = *(const f16x8*)&sA[16 + lrow][g * 8];
#pragma unroll
        for (int c = 0; c < 2; c++) {
            int col = w * 32 + c * 16 + lrow;
            f16x8 bh = *(const f16x8*)&Whp[(size_t)col * 128 + g * 8];
            f16x8 bl = *(const f16x8*)&Wlp[(size_t)col * 128 + g * 8];
            acc[0][c] = __builtin_amdgcn_mfma_f32_16x16x32_f16(a0, bh, acc[0][c], 0, 0, 0);
            acc[0][c] = __builtin_amdgcn_mfma_f32_16x16x32_f16(a0, bl, acc[0][c], 0, 0, 0);
            acc[1][c] = __builtin_amdgcn_mfma_f32_16x16x32_f16(a1, bh, acc[1][c], 0, 0, 0);
            acc[1][c] = __builtin_amdgcn_mfma_f32_16x16x32_f16(a1, bl, acc[1][c], 0, 0, 0);
        }
    }

    // ---- epilogue: bias + relu; C/D frag: col=lane&15, row=(lane>>4)*4+reg ----
    float bcol[2];
    bcol[0] = bias[w * 32 + 0 * 16 + lrow];
    bcol[1] = bias[w * 32 + 1 * 16 + lrow];
#pragma unroll
    for (int m = 0; m < 2; m++) {
        int rbase = row0 + m * 16 + kg * 4;
#pragma unroll
        for (int j = 0; j < 4; j++) {
            int rowi = rbase + j;
            float dvr = write_h ? dinv[rowi] : 0.f;
#pragma unroll
            for (int c = 0; c < 2; c++) {
                float o = fmaxf(acc[m][c][j] + bcol[c], 0.f);
                float o2 = __shfl_xor(o, 1);  // partner col (lane^1): same row, col^1
                int col = w * 32 + c * 16 + lrow;
                if (write_out)
                    __builtin_nontemporal_store(o, out + (size_t)rowi * 128 + col);
                if (write_h && !(f & 1))
                    xs_out[(size_t)rowi * 64 + (col >> 1)] =
                        __floats2half2_rn(dvr * o, dvr * o2);
            }
        }
    }
}

// ---------------- launch ----------------

extern "C" void kernel_launch(void* const* d_in, const int* in_sizes, int n_in,
                              void* d_out, int out_size, void* d_ws, size_t ws_size,
                              hipStream_t stream) {
    const int* edge = (const int*)d_in[0];   // [2, E] int32
    const float* emb = (const float*)d_in[1];
    const float* Ws = (const float*)d_in[2]; // [L, D, D]
    const float* bs = (const float*)d_in[3]; // [L, D]
    float* out = (float*)d_out;

    const int n = N_NODES, e = N_EDGES;
    const int* row = edge;       // sources
    const int* col = edge + e;   // targets

    char* p = (char*)d_ws;
    _Float16* Ah = (_Float16*)p;
    int* hmat = (int*)p;                      // aliases Ah (dead until first agg)
    int* hoff = hmat + (size_t)NBLK_E * NB;
    p += (size_t)n * D * 2;                   // 25.6 MB  (single fp16 A plane)
    __half2* xs = (__half2*)p;                // 25.6 MB (pre-scaled fp16 features)
    unsigned* bucketbuf = (unsigned*)p;       // aliases xs: dead before cast runs
    p += (size_t)n * D * 2;
    int* csr_src  = (int*)p;    p += (size_t)e * 4;           // 6.4 MB
    float* dinv   = (float*)p;  p += (size_t)n * 4;
    int* offsets  = (int*)p;    p += (size_t)(n + 1) * 4;
    int* btot     = (int*)p;    p += (size_t)NB * 4;
    int* bstart   = (int*)p;    p += (size_t)(NB + 1) * 4;
    _Float16* WhT = (_Float16*)p; p += (size_t)NLAYERS * D * D * 2;  // 98 KB
    _Float16* WlT = (_Float16*)p; p += (size_t)NLAYERS * D * D * 2;  // 98 KB

    hist1_kernel<<<NBLK_E, 512, 0, stream>>>(col, hmat);
    btot_kernel<<<(NB + 255) / 256, 256, 0, stream>>>(hmat, btot);
    bscan_kernel<<<1, 1024, 0, stream>>>(btot, bstart, NB, e);
    hoff_kernel<<<(NB + 255) / 256, 256, 0, stream>>>(hmat, bstart, hoff);
    scatter_kernel<<<NBLK_E, 512, 0, stream>>>(row, col, hoff, bucketbuf);
    fill2_kernel<<<NB, 256, 0, stream>>>(bucketbuf, bstart, offsets, dinv, csr_src, n, e);
    wsplit_kernel<<<dim3(128, NLAYERS), 128, 0, stream>>>(Ws, WhT, WlT);

    int n2 = n * 64;  // half2 count
    cast_kernel<<<(n2 + 255) / 256, 256, 0, stream>>>((const float2*)emb, dinv, xs, n2);

    const int half = n / 2;  // 50000
    for (int l = 0; l < NLAYERS; l++) {
        agg_kernel<<<half, 64, 0, stream>>>(xs, offsets, (unsigned*)Ah,
                                            dinv, csr_src, 0);
        agg_kernel<<<half, 64, 0, stream>>>(xs, offsets, (unsigned*)Ah,
                                            dinv, csr_src, half);
        gemm_mfma_kernel<<<n / 32, 256, 0, stream>>>(
            Ah, WhT + (size_t)l * D * D, WlT + (size_t)l * D * D,
            bs + (size_t)l * D, out, xs, dinv,
            (l < NLAYERS - 1) ? 1 : 0, (l == NLAYERS - 1) ? 1 : 0);
    }
}

// Round 17
// 463.381 us; speedup vs baseline: 1.3520x; 1.0299x over previous
//
#include <hip/hip_runtime.h>
#include <hip/hip_fp16.h>
#include <cstdint>
#include <cstddef>

#define N_NODES 100000
#define N_EDGES 1600000
#define D 128
#define NLAYERS 3
#define NB 3125       // buckets of 32 nodes
#define NBLK_E 512    // edge-phase blocks (R16: 128->512; scatter was 47us at 7% occ)
#define EPB 3125      // edges per block: 1600000/512
#define NCHUNK 8      // b-chunks of 64 for the hoff prefix decomposition
#define ENT_CAP 1024  // fill2 LDS entries; bucket max ~600 (22 sigma)

typedef float f2v __attribute__((ext_vector_type(2)));
typedef _Float16 f16x8 __attribute__((ext_vector_type(8)));
typedef float f32x4 __attribute__((ext_vector_type(4)));
typedef unsigned u32x4 __attribute__((ext_vector_type(4)));

// ---------------- CSR build: LDS-histogram counting sort ----------------
// R11: global-atomic CSR was +127us (scatter WRITE amplification 17x from
// cross-XCD line ping-pong) — bucket sort localizes CSR writes per block.
// R16: grid reshape for parallelism. NBLK_E 128->512 (scatter/hist at 2
// blocks/CU, ~6 serial iters instead of 24). The b-loop kernels (btot/hoff)
// are split over b-chunks so their serial depth stays 64, not 512:
//   bpart[c][j]  = sum over b in chunk c of hmat[b][j]        (grid 13x8)
//   bstart       = exclusive scan of col totals (Σ_c bpart)   (1 block)
//   hoff[b][j]   = Σ_{c<chunk(b)} bpart[c][j] + local prefix  (grid 13x8)
//   scatter cur  = bstart[j] + hoff[b][j]                     (folded init)

__global__ __launch_bounds__(512) void hist1_kernel(const int* __restrict__ col,
                                                    int* __restrict__ hmat) {
    __shared__ int hist[NB];
    int b = blockIdx.x, t = threadIdx.x;
    for (int j = t; j < NB; j += 512) hist[j] = 0;
    __syncthreads();
    int base = b * EPB;
    for (int i = t; i < EPB; i += 512) {
        int c = col[base + i];
        atomicAdd(&hist[c >> 5], 1);  // LDS atomic
    }
    __syncthreads();
    for (int j = t; j < NB; j += 512) hmat[b * NB + j] = hist[j];
}

// bpart[c][j] = sum over b in [c*64, c*64+64) of hmat[b][j]. Coalesced.
__global__ __launch_bounds__(256) void bpart_kernel(const int* __restrict__ hmat,
                                                    int* __restrict__ bpart) {
    int j = blockIdx.x * 256 + threadIdx.x;
    int c = blockIdx.y;
    if (j < NB) {
        int s = 0;
        int b0 = c * 64;
        for (int b = b0; b < b0 + 64; b++) s += hmat[(size_t)b * NB + j];
        bpart[c * NB + j] = s;
    }
}

// Single-block exclusive scan over 3125 column totals (Σ_c bpart) -> bstart.
__global__ void bscan_kernel(const int* __restrict__ bpart, int* __restrict__ bstart,
                             int nb, int e) {
    __shared__ int lsum[1024];
    int t = threadIdx.x;
    int vals[4];
    int v0 = 0;
#pragma unroll
    for (int j = 0; j < 4; j++) {
        int idx = t * 4 + j;
        int c = 0;
        if (idx < nb) {
#pragma unroll
            for (int k = 0; k < NCHUNK; k++) c += bpart[k * NB + idx];
        }
        vals[j] = c;
        v0 += c;
    }
    lsum[t] = v0;
    __syncthreads();
    for (int off = 1; off < 1024; off <<= 1) {
        int x = (t >= off) ? lsum[t - off] : 0;
        __syncthreads();
        lsum[t] += x;
        __syncthreads();
    }
    int base = lsum[t] - v0;  // exclusive
#pragma unroll
    for (int j = 0; j < 4; j++) {
        int idx = t * 4 + j;
        if (idx < nb) {
            bstart[idx] = base;
            base += vals[j];
        }
    }
    if (t == 0) bstart[nb] = e;
}

// hoff[b][j] = raw per-column prefix (Σ_{b'<b} hmat[b'][j]); bstart added
// later in scatter's cursor init. Chunk base = Σ_{c<chunk} bpart[c][j].
__global__ __launch_bounds__(256) void hoff2_kernel(const int* __restrict__ hmat,
                                                    const int* __restrict__ bpart,
                                                    int* __restrict__ hoff) {
    int j = blockIdx.x * 256 + threadIdx.x;
    int c = blockIdx.y;
    if (j < NB) {
        int run = 0;
        for (int k = 0; k < c; k++) run += bpart[k * NB + j];
        int b0 = c * 64;
        for (int b = b0; b < b0 + 64; b++) {
            hoff[(size_t)b * NB + j] = run;
            run += hmat[(size_t)b * NB + j];
        }
    }
}

// Scatter edges to exact bucket-sorted positions. LDS cursors, no global atomics.
__global__ __launch_bounds__(512) void scatter_kernel(const int* __restrict__ row,
                                                      const int* __restrict__ col,
                                                      const int* __restrict__ hoff,
                                                      const int* __restrict__ bstart,
                                                      unsigned* __restrict__ bucketbuf) {
    __shared__ int cur[NB];
    int b = blockIdx.x, t = threadIdx.x;
    for (int j = t; j < NB; j += 512)
        cur[j] = hoff[(size_t)b * NB + j] + bstart[j];
    __syncthreads();
    int base = b * EPB;
    for (int i = t; i < EPB; i += 512) {
        int r = row[base + i], c = col[base + i];
        int pos = atomicAdd(&cur[c >> 5], 1);  // LDS atomic
        bucketbuf[pos] = ((unsigned)r << 5) | (unsigned)(c & 31);
    }
}

// One block per bucket: LDS histogram of 32 local cols -> per-node offsets,
// dinv, and localized CSR scatter (contiguous ~2KB range, LDS cursors).
__global__ void fill2_kernel(const unsigned* __restrict__ bucketbuf, const int* __restrict__ bstart,
                             int* __restrict__ offsets, float* __restrict__ dinv,
                             int* __restrict__ src, int n, int e) {
    __shared__ unsigned ent[ENT_CAP];
    __shared__ int hist[32];
    __shared__ int cur[32];
    __shared__ int loff[32];
    int b = blockIdx.x, t = threadIdx.x;
    int s0 = bstart[b];
    int cnt = bstart[b + 1] - s0;
    if (cnt > ENT_CAP) cnt = ENT_CAP;
    if (t < 32) hist[t] = 0;
    __syncthreads();
    for (int i = t; i < cnt; i += 256) {
        unsigned v = bucketbuf[s0 + i];
        ent[i] = v;
        atomicAdd(&hist[v & 31], 1);
    }
    __syncthreads();
    if (t == 0) {
        int run = s0;
#pragma unroll
        for (int j = 0; j < 32; j++) {
            loff[j] = run;
            run += hist[j];
        }
    }
    __syncthreads();
    if (t < 32) {
        int node = b * 32 + t;
        int o = loff[t];
        offsets[node] = o;
        cur[t] = o;
        dinv[node] = rsqrtf((float)(hist[t] + 1));  // +1 self loop
    }
    if (b == 0 && t == 0) offsets[n] = e;
    __syncthreads();
    for (int i = t; i < cnt; i += 256) {
        unsigned v = ent[i];
        int pos = atomicAdd(&cur[v & 31], 1);
        src[pos] = (int)(v >> 5);
    }
}

// ---------------- per-layer kernels ----------------

// Cast + pre-scale: xs[v] = fp16(dinv[v] * emb[v]). Pre-scaling removes the
// per-edge dinv[src] gather + multiply from the agg inner loop.
__global__ void cast_kernel(const float2* __restrict__ in, const float* __restrict__ dinv,
                            __half2* __restrict__ out, int n2) {
    int i = blockIdx.x * 256 + threadIdx.x;
    if (i < n2) {
        float d = dinv[i >> 6];  // wave-uniform (64 half2 per node)
        float2 v = in[i];
        out[i] = __floats2half2_rn(d * v.x, d * v.y);
    }
}

// W pre-split for the hi/lo fp16 MFMA: WhT/WlT[l][col][k] (transposed,
// fragment-ready). w = wh + wl, wh=fp16(w), wl=fp16(w-wh). W stays hi/lo
// (L2-resident, costs one extra MFMA only); the A-side lo plane was dropped
// in R15 (absmax unchanged at 9.77e-4).
__global__ void wsplit_kernel(const float* __restrict__ W,
                              _Float16* __restrict__ Wh, _Float16* __restrict__ Wl) {
    int c = blockIdx.x, l = blockIdx.y, k = threadIdx.x;  // 128 threads
    float w = W[(size_t)l * 16384 + k * 128 + c];
    _Float16 h = (_Float16)w;
    float r = w - (float)h;
    Wh[(size_t)l * 16384 + c * 128 + k] = h;
    Wl[(size_t)l * 16384 + c * 128 + k] = (_Float16)r;
}

// UNFUSED aggregation (R5/R10-verified 61.5us structure, 8-deep MLP).
// One 64-thread block (=1 wave) per node; xs PRE-SCALED (dinv*x):
//   a[v] = dinv[v] * ( xs[v] + sum_e xs[src_e] ), fp32 accum -> fp16 A.
// Regular (non-NT) stores: A intermediate stays L2/L3-resident (R12/R15).
__global__ void agg_kernel(const __half2* __restrict__ xs, const int* __restrict__ offs,
                           unsigned* __restrict__ Ah,
                           const float* __restrict__ dinv, const int* __restrict__ src,
                           int vbase) {
    int v = vbase + blockIdx.x;
    int f = threadIdx.x;  // 0..63
    float dv = dinv[v];
    float2 a0 = __half22float2(xs[(size_t)v * 64 + f]);  // self term (already scaled)
    float ax = a0.x;
    float ay = a0.y;
    int i = offs[v], s1 = offs[v + 1];
    for (; i + 7 < s1; i += 8) {
        int s[8];
#pragma unroll
        for (int j = 0; j < 8; j++) s[j] = src[i + j];
        float2 x[8];
#pragma unroll
        for (int j = 0; j < 8; j++) x[j] = __half22float2(xs[(size_t)s[j] * 64 + f]);
#pragma unroll
        for (int j = 0; j < 8; j++) {
            ax += x[j].x;
            ay += x[j].y;
        }
    }
    if (i < s1) {  // masked tail group
        int last = s1 - 1;
        int s[8];
        float m[8];
#pragma unroll
        for (int j = 0; j < 8; j++) {
            int idx = i + j;
            bool in = idx < s1;
            s[j] = src[in ? idx : last];
            m[j] = in ? 1.0f : 0.0f;
        }
        float2 x[8];
#pragma unroll
        for (int j = 0; j < 8; j++) x[j] = __half22float2(xs[(size_t)s[j] * 64 + f]);
#pragma unroll
        for (int j = 0; j < 8; j++) {
            ax += m[j] * x[j].x;
            ay += m[j] * x[j].y;
        }
    }
    float rx = dv * ax, ry = dv * ay;
    __half2 h2 = __floats2half2_rn(rx, ry);
    Ah[(size_t)v * 64 + f] = __builtin_bit_cast(unsigned, h2);   // regular: L2/L3-resident
}

// out[M x 128] = relu(A[M x 128] @ W[128 x 128] + bias) via fp16 MFMA.
// BM=32, 3125 blocks; single fp16 A plane, W hi/lo (h = a.wh + a.wl).
// Regular loads on the A path (L2/L3 fill, R12 lesson).
__global__ __launch_bounds__(256, 6) void gemm_mfma_kernel(
    const _Float16* __restrict__ Ahp,
    const _Float16* __restrict__ Whp, const _Float16* __restrict__ Wlp,  // [col][k]
    const float* __restrict__ bias, float* __restrict__ out,
    __half2* __restrict__ xs_out, const float* __restrict__ dinv,
    int write_h, int write_out) {
    __shared__ _Float16 sA[32][136];  // [row][16 kg * 8 + 8 pad] = 8.7 KB
    int t = threadIdx.x;
    int f = t & 63;   // lane
    int w = t >> 6;   // wave 0..3 -> cols w*32 .. w*32+31
    int row0 = blockIdx.x * 32;

    // ---- stage A tile: 512 qwords (32 rows x 16), 2 per thread ----
    const u32x4* Aq = (const u32x4*)Ahp;
#pragma unroll
    for (int i = 0; i < 2; i++) {
        int qid = t + 256 * i;          // 0..511, bijective over (r, k2)
        int r = qid >> 4;               // 0..31
        int k2 = qid & 15;              // 16B k-group
        u32x4 v = Aq[(size_t)(row0 + r) * 16 + k2];   // regular load: L2/L3 fill
        *(u32x4*)&sA[r][k2 * 8] = v;
    }
    __syncthreads();

    // ---- MFMA: rows 0..31 (2 m-frags) x wave's 32 cols (2 col-frags) ----
    int lrow = f & 15, kg = f >> 4;
    f32x4 acc[2][2];  // [m][c]
#pragma unroll
    for (int m = 0; m < 2; m++)
#pragma unroll
        for (int c = 0; c < 2; c++) acc[m][c] = (f32x4){0.f, 0.f, 0.f, 0.f};

#pragma unroll
    for (int ks = 0; ks < 4; ks++) {
        int g = ks * 4 + kg;  // 8-element k-group index
        f16x8 a0 = *(const f16x8*)&sA[lrow][g * 8];
        f16x8 a1 = *(const f16x8*)&sA[16 + lrow][g * 8];
#pragma unroll
        for (int c = 0; c < 2; c++) {
            int col = w * 32 + c * 16 + lrow;
            f16x8 bh = *(const f16x8*)&Whp[(size_t)col * 128 + g * 8];
            f16x8 bl = *(const f16x8*)&Wlp[(size_t)col * 128 + g * 8];
            acc[0][c] = __builtin_amdgcn_mfma_f32_16x16x32_f16(a0, bh, acc[0][c], 0, 0, 0);
            acc[0][c] = __builtin_amdgcn_mfma_f32_16x16x32_f16(a0, bl, acc[0][c], 0, 0, 0);
            acc[1][c] = __builtin_amdgcn_mfma_f32_16x16x32_f16(a1, bh, acc[1][c], 0, 0, 0);
            acc[1][c] = __builtin_amdgcn_mfma_f32_16x16x32_f16(a1, bl, acc[1][c], 0, 0, 0);
        }
    }

    // ---- epilogue: bias + relu; C/D frag: col=lane&15, row=(lane>>4)*4+reg ----
    float bcol[2];
    bcol[0] = bias[w * 32 + 0 * 16 + lrow];
    bcol[1] = bias[w * 32 + 1 * 16 + lrow];
#pragma unroll
    for (int m = 0; m < 2; m++) {
        int rbase = row0 + m * 16 + kg * 4;
#pragma unroll
        for (int j = 0; j < 4; j++) {
            int rowi = rbase + j;
            float dvr = write_h ? dinv[rowi] : 0.f;
#pragma unroll
            for (int c = 0; c < 2; c++) {
                float o = fmaxf(acc[m][c][j] + bcol[c], 0.f);
                float o2 = __shfl_xor(o, 1);  // partner col (lane^1): same row, col^1
                int col = w * 32 + c * 16 + lrow;
                if (write_out)
                    __builtin_nontemporal_store(o, out + (size_t)rowi * 128 + col);
                if (write_h && !(f & 1))
                    xs_out[(size_t)rowi * 64 + (col >> 1)] =
                        __floats2half2_rn(dvr * o, dvr * o2);
            }
        }
    }
}

// ---------------- launch ----------------

extern "C" void kernel_launch(void* const* d_in, const int* in_sizes, int n_in,
                              void* d_out, int out_size, void* d_ws, size_t ws_size,
                              hipStream_t stream) {
    const int* edge = (const int*)d_in[0];   // [2, E] int32
    const float* emb = (const float*)d_in[1];
    const float* Ws = (const float*)d_in[2]; // [L, D, D]
    const float* bs = (const float*)d_in[3]; // [L, D]
    float* out = (float*)d_out;

    const int n = N_NODES, e = N_EDGES;
    const int* row = edge;       // sources
    const int* col = edge + e;   // targets

    char* p = (char*)d_ws;
    _Float16* Ah = (_Float16*)p;
    int* hmat = (int*)p;                      // aliases Ah (dead until first agg)
    int* hoff = hmat + (size_t)NBLK_E * NB;   // 6.4 MB each
    int* bpart = hoff + (size_t)NBLK_E * NB;  // 100 KB
    p += (size_t)n * D * 2;                   // 25.6 MB  (single fp16 A plane)
    __half2* xs = (__half2*)p;                // 25.6 MB (pre-scaled fp16 features)
    unsigned* bucketbuf = (unsigned*)p;       // aliases xs: dead before cast runs
    p += (size_t)n * D * 2;
    int* csr_src  = (int*)p;    p += (size_t)e * 4;           // 6.4 MB
    float* dinv   = (float*)p;  p += (size_t)n * 4;
    int* offsets  = (int*)p;    p += (size_t)(n + 1) * 4;
    int* bstart   = (int*)p;    p += (size_t)(NB + 1) * 4;
    _Float16* WhT = (_Float16*)p; p += (size_t)NLAYERS * D * D * 2;  // 98 KB
    _Float16* WlT = (_Float16*)p; p += (size_t)NLAYERS * D * D * 2;  // 98 KB

    hist1_kernel<<<NBLK_E, 512, 0, stream>>>(col, hmat);
    bpart_kernel<<<dim3(13, NCHUNK), 256, 0, stream>>>(hmat, bpart);
    bscan_kernel<<<1, 1024, 0, stream>>>(bpart, bstart, NB, e);
    hoff2_kernel<<<dim3(13, NCHUNK), 256, 0, stream>>>(hmat, bpart, hoff);
    scatter_kernel<<<NBLK_E, 512, 0, stream>>>(row, col, hoff, bstart, bucketbuf);
    fill2_kernel<<<NB, 256, 0, stream>>>(bucketbuf, bstart, offsets, dinv, csr_src, n, e);
    wsplit_kernel<<<dim3(128, NLAYERS), 128, 0, stream>>>(Ws, WhT, WlT);

    int n2 = n * 64;  // half2 count
    cast_kernel<<<(n2 + 255) / 256, 256, 0, stream>>>((const float2*)emb, dinv, xs, n2);

    const int half = n / 2;  // 50000
    for (int l = 0; l < NLAYERS; l++) {
        agg_kernel<<<half, 64, 0, stream>>>(xs, offsets, (unsigned*)Ah,
                                            dinv, csr_src, 0);
        agg_kernel<<<half, 64, 0, stream>>>(xs, offsets, (unsigned*)Ah,
                                            dinv, csr_src, half);
        gemm_mfma_kernel<<<n / 32, 256, 0, stream>>>(
            Ah, WhT + (size_t)l * D * D, WlT + (size_t)l * D * D,
            bs + (size_t)l * D, out, xs, dinv,
            (l < NLAYERS - 1) ? 1 : 0, (l == NLAYERS - 1) ? 1 : 0);
    }
}

// Round 18
// 455.756 us; speedup vs baseline: 1.3746x; 1.0167x over previous
//
#include <hip/hip_runtime.h>
#include <hip/hip_fp16.h>
#include <cstdint>
#include <cstddef>

#define N_NODES 100000
#define N_EDGES 1600000
#define D 128
#define NLAYERS 3
#define NB 3125       // buckets of 32 nodes
#define NBLK_E 512    // edge-phase blocks (R16: scatter 47us@7%occ -> 512 blocks)
#define EPB 3125      // edges per block: 1600000/512
#define NCHUNK 8      // b-chunks of 64 for the hoff prefix decomposition
#define ENT_CAP 1024  // fill2 LDS entries; bucket max ~600 (22 sigma)

typedef float f2v __attribute__((ext_vector_type(2)));
typedef _Float16 f16x8 __attribute__((ext_vector_type(8)));
typedef float f32x4 __attribute__((ext_vector_type(4)));
typedef unsigned u32x4 __attribute__((ext_vector_type(4)));

// ---------------- CSR build: LDS-histogram counting sort ----------------
// R11: global-atomic CSR was +127us (scatter WRITE amplification 17x from
// cross-XCD line ping-pong) — bucket sort localizes CSR writes per block.
// R16 grid reshape: NBLK_E=512, b-chunked prefix kernels. Verified -14us.

__global__ __launch_bounds__(512) void hist1_kernel(const int* __restrict__ col,
                                                    int* __restrict__ hmat) {
    __shared__ int hist[NB];
    int b = blockIdx.x, t = threadIdx.x;
    for (int j = t; j < NB; j += 512) hist[j] = 0;
    __syncthreads();
    int base = b * EPB;
    for (int i = t; i < EPB; i += 512) {
        int c = col[base + i];
        atomicAdd(&hist[c >> 5], 1);  // LDS atomic
    }
    __syncthreads();
    for (int j = t; j < NB; j += 512) hmat[b * NB + j] = hist[j];
}

// bpart[c][j] = sum over b in [c*64, c*64+64) of hmat[b][j]. Coalesced.
__global__ __launch_bounds__(256) void bpart_kernel(const int* __restrict__ hmat,
                                                    int* __restrict__ bpart) {
    int j = blockIdx.x * 256 + threadIdx.x;
    int c = blockIdx.y;
    if (j < NB) {
        int s = 0;
        int b0 = c * 64;
        for (int b = b0; b < b0 + 64; b++) s += hmat[(size_t)b * NB + j];
        bpart[c * NB + j] = s;
    }
}

// Single-block exclusive scan over 3125 column totals (Σ_c bpart) -> bstart.
__global__ void bscan_kernel(const int* __restrict__ bpart, int* __restrict__ bstart,
                             int nb, int e) {
    __shared__ int lsum[1024];
    int t = threadIdx.x;
    int vals[4];
    int v0 = 0;
#pragma unroll
    for (int j = 0; j < 4; j++) {
        int idx = t * 4 + j;
        int c = 0;
        if (idx < nb) {
#pragma unroll
            for (int k = 0; k < NCHUNK; k++) c += bpart[k * NB + idx];
        }
        vals[j] = c;
        v0 += c;
    }
    lsum[t] = v0;
    __syncthreads();
    for (int off = 1; off < 1024; off <<= 1) {
        int x = (t >= off) ? lsum[t - off] : 0;
        __syncthreads();
        lsum[t] += x;
        __syncthreads();
    }
    int base = lsum[t] - v0;  // exclusive
#pragma unroll
    for (int j = 0; j < 4; j++) {
        int idx = t * 4 + j;
        if (idx < nb) {
            bstart[idx] = base;
            base += vals[j];
        }
    }
    if (t == 0) bstart[nb] = e;
}

// hoff[b][j] = raw per-column prefix (Σ_{b'<b} hmat[b'][j]); bstart added
// in scatter's cursor init. Chunk base = Σ_{c<chunk} bpart[c][j].
__global__ __launch_bounds__(256) void hoff2_kernel(const int* __restrict__ hmat,
                                                    const int* __restrict__ bpart,
                                                    int* __restrict__ hoff) {
    int j = blockIdx.x * 256 + threadIdx.x;
    int c = blockIdx.y;
    if (j < NB) {
        int run = 0;
        for (int k = 0; k < c; k++) run += bpart[k * NB + j];
        int b0 = c * 64;
        for (int b = b0; b < b0 + 64; b++) {
            hoff[(size_t)b * NB + j] = run;
            run += hmat[(size_t)b * NB + j];
        }
    }
}

// Scatter edges to exact bucket-sorted positions. LDS cursors, no global atomics.
__global__ __launch_bounds__(512) void scatter_kernel(const int* __restrict__ row,
                                                      const int* __restrict__ col,
                                                      const int* __restrict__ hoff,
                                                      const int* __restrict__ bstart,
                                                      unsigned* __restrict__ bucketbuf) {
    __shared__ int cur[NB];
    int b = blockIdx.x, t = threadIdx.x;
    for (int j = t; j < NB; j += 512)
        cur[j] = hoff[(size_t)b * NB + j] + bstart[j];
    __syncthreads();
    int base = b * EPB;
    for (int i = t; i < EPB; i += 512) {
        int r = row[base + i], c = col[base + i];
        int pos = atomicAdd(&cur[c >> 5], 1);  // LDS atomic
        bucketbuf[pos] = ((unsigned)r << 5) | (unsigned)(c & 31);
    }
}

// One block per bucket: LDS histogram of 32 local cols -> per-node offsets,
// dinv, and localized CSR scatter (contiguous ~2KB range, LDS cursors).
__global__ void fill2_kernel(const unsigned* __restrict__ bucketbuf, const int* __restrict__ bstart,
                             int* __restrict__ offsets, float* __restrict__ dinv,
                             int* __restrict__ src, int n, int e) {
    __shared__ unsigned ent[ENT_CAP];
    __shared__ int hist[32];
    __shared__ int cur[32];
    __shared__ int loff[32];
    int b = blockIdx.x, t = threadIdx.x;
    int s0 = bstart[b];
    int cnt = bstart[b + 1] - s0;
    if (cnt > ENT_CAP) cnt = ENT_CAP;
    if (t < 32) hist[t] = 0;
    __syncthreads();
    for (int i = t; i < cnt; i += 256) {
        unsigned v = bucketbuf[s0 + i];
        ent[i] = v;
        atomicAdd(&hist[v & 31], 1);
    }
    __syncthreads();
    if (t == 0) {
        int run = s0;
#pragma unroll
        for (int j = 0; j < 32; j++) {
            loff[j] = run;
            run += hist[j];
        }
    }
    __syncthreads();
    if (t < 32) {
        int node = b * 32 + t;
        int o = loff[t];
        offsets[node] = o;
        cur[t] = o;
        dinv[node] = rsqrtf((float)(hist[t] + 1));  // +1 self loop
    }
    if (b == 0 && t == 0) offsets[n] = e;
    __syncthreads();
    for (int i = t; i < cnt; i += 256) {
        unsigned v = ent[i];
        int pos = atomicAdd(&cur[v & 31], 1);
        src[pos] = (int)(v >> 5);
    }
}

// ---------------- per-layer kernels ----------------

// Cast + pre-scale: xs[v] = fp16(dinv[v] * emb[v]). Pre-scaling removes the
// per-edge dinv[src] gather + multiply from the agg inner loop.
__global__ void cast_kernel(const float2* __restrict__ in, const float* __restrict__ dinv,
                            __half2* __restrict__ out, int n2) {
    int i = blockIdx.x * 256 + threadIdx.x;
    if (i < n2) {
        float d = dinv[i >> 6];  // wave-uniform (64 half2 per node)
        float2 v = in[i];
        out[i] = __floats2half2_rn(d * v.x, d * v.y);
    }
}

// W pre-split for the hi/lo fp16 MFMA: WhT/WlT[l][col][k] (transposed,
// fragment-ready). w = wh + wl; A-side lo plane dropped in R15 (absmax
// unchanged at 9.77e-4 — xs-gather rounding dominates).
__global__ void wsplit_kernel(const float* __restrict__ W,
                              _Float16* __restrict__ Wh, _Float16* __restrict__ Wl) {
    int c = blockIdx.x, l = blockIdx.y, k = threadIdx.x;  // 128 threads
    float w = W[(size_t)l * 16384 + k * 128 + c];
    _Float16 h = (_Float16)w;
    float r = w - (float)h;
    Wh[(size_t)l * 16384 + c * 128 + k] = h;
    Wl[(size_t)l * 16384 + c * 128 + k] = (_Float16)r;
}

// UNFUSED aggregation. One 64-thread block (=1 wave) per node; xs PRE-SCALED:
//   a[v] = dinv[v] * ( xs[v] + sum_e xs[src_e] ), fp32 accum -> fp16 A.
// R17 change: main group 8 -> 16-deep. R17 counters: agg at 3.25 TB/s HBM
// (52% of achievable), occupancy 76%, VALU 25% — MLP-bound at the group
// boundary (8 gathers drain to zero before the adds). 16-deep doubles
// in-flight bytes/wave. Register budget ~60 VGPR — just under the 64-VGPR
// occupancy cliff; VGPR_Count next round adjudicates.
// Regular (non-NT) stores: A intermediate stays L2/L3-resident (R12/R15).
__global__ void agg_kernel(const __half2* __restrict__ xs, const int* __restrict__ offs,
                           unsigned* __restrict__ Ah,
                           const float* __restrict__ dinv, const int* __restrict__ src) {
    int v = blockIdx.x;
    int f = threadIdx.x;  // 0..63
    float dv = dinv[v];
    float2 a0 = __half22float2(xs[(size_t)v * 64 + f]);  // self term (already scaled)
    float ax = a0.x;
    float ay = a0.y;
    int i = offs[v], s1 = offs[v + 1];
    for (; i + 15 < s1; i += 16) {  // 16-deep main group
        int s[16];
#pragma unroll
        for (int j = 0; j < 16; j++) s[j] = src[i + j];
        float2 x[16];
#pragma unroll
        for (int j = 0; j < 16; j++) x[j] = __half22float2(xs[(size_t)s[j] * 64 + f]);
#pragma unroll
        for (int j = 0; j < 16; j++) {
            ax += x[j].x;
            ay += x[j].y;
        }
    }
    if (i + 7 < s1) {  // 8-deep
        int s[8];
#pragma unroll
        for (int j = 0; j < 8; j++) s[j] = src[i + j];
        float2 x[8];
#pragma unroll
        for (int j = 0; j < 8; j++) x[j] = __half22float2(xs[(size_t)s[j] * 64 + f]);
#pragma unroll
        for (int j = 0; j < 8; j++) {
            ax += x[j].x;
            ay += x[j].y;
        }
        i += 8;
    }
    if (i < s1) {  // masked tail group
        int last = s1 - 1;
        int s[8];
        float m[8];
#pragma unroll
        for (int j = 0; j < 8; j++) {
            int idx = i + j;
            bool in = idx < s1;
            s[j] = src[in ? idx : last];
            m[j] = in ? 1.0f : 0.0f;
        }
        float2 x[8];
#pragma unroll
        for (int j = 0; j < 8; j++) x[j] = __half22float2(xs[(size_t)s[j] * 64 + f]);
#pragma unroll
        for (int j = 0; j < 8; j++) {
            ax += m[j] * x[j].x;
            ay += m[j] * x[j].y;
        }
    }
    float rx = dv * ax, ry = dv * ay;
    __half2 h2 = __floats2half2_rn(rx, ry);
    Ah[(size_t)v * 64 + f] = __builtin_bit_cast(unsigned, h2);   // regular: L2/L3-resident
}

// out[M x 128] = relu(A[M x 128] @ W[128 x 128] + bias) via fp16 MFMA.
// BM=32, 3125 blocks; single fp16 A plane, W hi/lo (h = a.wh + a.wl).
// Regular loads on the A path (L2/L3 fill, R12 lesson).
__global__ __launch_bounds__(256, 6) void gemm_mfma_kernel(
    const _Float16* __restrict__ Ahp,
    const _Float16* __restrict__ Whp, const _Float16* __restrict__ Wlp,  // [col][k]
    const float* __restrict__ bias, float* __restrict__ out,
    __half2* __restrict__ xs_out, const float* __restrict__ dinv,
    int write_h, int write_out) {
    __shared__ _Float16 sA[32][136];  // [row][16 kg * 8 + 8 pad] = 8.7 KB
    int t = threadIdx.x;
    int f = t & 63;   // lane
    int w = t >> 6;   // wave 0..3 -> cols w*32 .. w*32+31
    int row0 = blockIdx.x * 32;

    // ---- stage A tile: 512 qwords (32 rows x 16), 2 per thread ----
    const u32x4* Aq = (const u32x4*)Ahp;
#pragma unroll
    for (int i = 0; i < 2; i++) {
        int qid = t + 256 * i;          // 0..511, bijective over (r, k2)
        int r = qid >> 4;               // 0..31
        int k2 = qid & 15;              // 16B k-group
        u32x4 v = Aq[(size_t)(row0 + r) * 16 + k2];   // regular load: L2/L3 fill
        *(u32x4*)&sA[r][k2 * 8] = v;
    }
    __syncthreads();

    // ---- MFMA: rows 0..31 (2 m-frags) x wave's 32 cols (2 col-frags) ----
    int lrow = f & 15, kg = f >> 4;
    f32x4 acc[2][2];  // [m][c]
#pragma unroll
    for (int m = 0; m < 2; m++)
#pragma unroll
        for (int c = 0; c < 2; c++) acc[m][c] = (f32x4){0.f, 0.f, 0.f, 0.f};

#pragma unroll
    for (int ks = 0; ks < 4; ks++) {
        int g = ks * 4 + kg;  // 8-element k-group index
        f16x8 a0 = *(const f16x8*)&sA[lrow][g * 8];
        f16x8 a1 = *(const f16x8*)&sA[16 + lrow][g * 8];
#pragma unroll
        for (int c = 0; c < 2; c++) {
            int col = w * 32 + c * 16 + lrow;
            f16x8 bh = *(const f16x8*)&Whp[(size_t)col * 128 + g * 8];
            f16x8 bl = *(const f16x8*)&Wlp[(size_t)col * 128 + g * 8];
            acc[0][c] = __builtin_amdgcn_mfma_f32_16x16x32_f16(a0, bh, acc[0][c], 0, 0, 0);
            acc[0][c] = __builtin_amdgcn_mfma_f32_16x16x32_f16(a0, bl, acc[0][c], 0, 0, 0);
            acc[1][c] = __builtin_amdgcn_mfma_f32_16x16x32_f16(a1, bh, acc[1][c], 0, 0, 0);
            acc[1][c] = __builtin_amdgcn_mfma_f32_16x16x32_f16(a1, bl, acc[1][c], 0, 0, 0);
        }
    }

    // ---- epilogue: bias + relu; C/D frag: col=lane&15, row=(lane>>4)*4+reg ----
    float bcol[2];
    bcol[0] = bias[w * 32 + 0 * 16 + lrow];
    bcol[1] = bias[w * 32 + 1 * 16 + lrow];
#pragma unroll
    for (int m = 0; m < 2; m++) {
        int rbase = row0 + m * 16 + kg * 4;
#pragma unroll
        for (int j = 0; j < 4; j++) {
            int rowi = rbase + j;
            float dvr = write_h ? dinv[rowi] : 0.f;
#pragma unroll
            for (int c = 0; c < 2; c++) {
                float o = fmaxf(acc[m][c][j] + bcol[c], 0.f);
                float o2 = __shfl_xor(o, 1);  // partner col (lane^1): same row, col^1
                int col = w * 32 + c * 16 + lrow;
                if (write_out)
                    __builtin_nontemporal_store(o, out + (size_t)rowi * 128 + col);
                if (write_h && !(f & 1))
                    xs_out[(size_t)rowi * 64 + (col >> 1)] =
                        __floats2half2_rn(dvr * o, dvr * o2);
            }
        }
    }
}

// ---------------- launch ----------------

extern "C" void kernel_launch(void* const* d_in, const int* in_sizes, int n_in,
                              void* d_out, int out_size, void* d_ws, size_t ws_size,
                              hipStream_t stream) {
    const int* edge = (const int*)d_in[0];   // [2, E] int32
    const float* emb = (const float*)d_in[1];
    const float* Ws = (const float*)d_in[2]; // [L, D, D]
    const float* bs = (const float*)d_in[3]; // [L, D]
    float* out = (float*)d_out;

    const int n = N_NODES, e = N_EDGES;
    const int* row = edge;       // sources
    const int* col = edge + e;   // targets

    char* p = (char*)d_ws;
    _Float16* Ah = (_Float16*)p;
    int* hmat = (int*)p;                      // aliases Ah (dead until first agg)
    int* hoff = hmat + (size_t)NBLK_E * NB;   // 6.4 MB each
    int* bpart = hoff + (size_t)NBLK_E * NB;  // 100 KB
    p += (size_t)n * D * 2;                   // 25.6 MB  (single fp16 A plane)
    __half2* xs = (__half2*)p;                // 25.6 MB (pre-scaled fp16 features)
    unsigned* bucketbuf = (unsigned*)p;       // aliases xs: dead before cast runs
    p += (size_t)n * D * 2;
    int* csr_src  = (int*)p;    p += (size_t)e * 4;           // 6.4 MB
    float* dinv   = (float*)p;  p += (size_t)n * 4;
    int* offsets  = (int*)p;    p += (size_t)(n + 1) * 4;
    int* bstart   = (int*)p;    p += (size_t)(NB + 1) * 4;
    _Float16* WhT = (_Float16*)p; p += (size_t)NLAYERS * D * D * 2;  // 98 KB
    _Float16* WlT = (_Float16*)p; p += (size_t)NLAYERS * D * D * 2;  // 98 KB

    hist1_kernel<<<NBLK_E, 512, 0, stream>>>(col, hmat);
    bpart_kernel<<<dim3(13, NCHUNK), 256, 0, stream>>>(hmat, bpart);
    bscan_kernel<<<1, 1024, 0, stream>>>(bpart, bstart, NB, e);
    hoff2_kernel<<<dim3(13, NCHUNK), 256, 0, stream>>>(hmat, bpart, hoff);
    scatter_kernel<<<NBLK_E, 512, 0, stream>>>(row, col, hoff, bstart, bucketbuf);
    fill2_kernel<<<NB, 256, 0, stream>>>(bucketbuf, bstart, offsets, dinv, csr_src, n, e);
    wsplit_kernel<<<dim3(128, NLAYERS), 128, 0, stream>>>(Ws, WhT, WlT);

    int n2 = n * 64;  // half2 count
    cast_kernel<<<(n2 + 255) / 256, 256, 0, stream>>>((const float2*)emb, dinv, xs, n2);

    for (int l = 0; l < NLAYERS; l++) {
        agg_kernel<<<n, 64, 0, stream>>>(xs, offsets, (unsigned*)Ah, dinv, csr_src);
        gemm_mfma_kernel<<<n / 32, 256, 0, stream>>>(
            Ah, WhT + (size_t)l * D * D, WlT + (size_t)l * D * D,
            bs + (size_t)l * D, out, xs, dinv,
            (l < NLAYERS - 1) ? 1 : 0, (l == NLAYERS - 1) ? 1 : 0);
    }
}

// Round 19
// 452.473 us; speedup vs baseline: 1.3846x; 1.0073x over previous
//
#include <hip/hip_runtime.h>
#include <hip/hip_fp16.h>
#include <cstdint>
#include <cstddef>

#define N_NODES 100000
#define N_EDGES 1600000
#define D 128
#define NLAYERS 3
#define NB 3125       // buckets of 32 nodes
#define NBLK_E 512    // edge-phase blocks (R16: scatter 47us@7%occ -> 512 blocks)
#define EPB 3125      // edges per block: 1600000/512
#define NCHUNK 8      // b-chunks of 64 for the hoff prefix decomposition
#define ENT_CAP 1024  // fill2 LDS entries; bucket max ~600 (22 sigma)

typedef float f2v __attribute__((ext_vector_type(2)));
typedef _Float16 f16x8 __attribute__((ext_vector_type(8)));
typedef float f32x4 __attribute__((ext_vector_type(4)));
typedef unsigned u32x4 __attribute__((ext_vector_type(4)));

// ---------------- CSR build: LDS-histogram counting sort ----------------
// R11: global-atomic CSR was +127us (scatter WRITE amplification 17x from
// cross-XCD line ping-pong) — bucket sort localizes CSR writes per block.
// R16 grid reshape: NBLK_E=512, b-chunked prefix kernels. Verified -14us.

__global__ __launch_bounds__(512) void hist1_kernel(const int* __restrict__ col,
                                                    int* __restrict__ hmat) {
    __shared__ int hist[NB];
    int b = blockIdx.x, t = threadIdx.x;
    for (int j = t; j < NB; j += 512) hist[j] = 0;
    __syncthreads();
    int base = b * EPB;
    for (int i = t; i < EPB; i += 512) {
        int c = col[base + i];
        atomicAdd(&hist[c >> 5], 1);  // LDS atomic
    }
    __syncthreads();
    for (int j = t; j < NB; j += 512) hmat[b * NB + j] = hist[j];
}

// bpart[c][j] = sum over b in [c*64, c*64+64) of hmat[b][j]. Coalesced.
__global__ __launch_bounds__(256) void bpart_kernel(const int* __restrict__ hmat,
                                                    int* __restrict__ bpart) {
    int j = blockIdx.x * 256 + threadIdx.x;
    int c = blockIdx.y;
    if (j < NB) {
        int s = 0;
        int b0 = c * 64;
        for (int b = b0; b < b0 + 64; b++) s += hmat[(size_t)b * NB + j];
        bpart[c * NB + j] = s;
    }
}

// Single-block exclusive scan over 3125 column totals (Σ_c bpart) -> bstart.
__global__ void bscan_kernel(const int* __restrict__ bpart, int* __restrict__ bstart,
                             int nb, int e) {
    __shared__ int lsum[1024];
    int t = threadIdx.x;
    int vals[4];
    int v0 = 0;
#pragma unroll
    for (int j = 0; j < 4; j++) {
        int idx = t * 4 + j;
        int c = 0;
        if (idx < nb) {
#pragma unroll
            for (int k = 0; k < NCHUNK; k++) c += bpart[k * NB + idx];
        }
        vals[j] = c;
        v0 += c;
    }
    lsum[t] = v0;
    __syncthreads();
    for (int off = 1; off < 1024; off <<= 1) {
        int x = (t >= off) ? lsum[t - off] : 0;
        __syncthreads();
        lsum[t] += x;
        __syncthreads();
    }
    int base = lsum[t] - v0;  // exclusive
#pragma unroll
    for (int j = 0; j < 4; j++) {
        int idx = t * 4 + j;
        if (idx < nb) {
            bstart[idx] = base;
            base += vals[j];
        }
    }
    if (t == 0) bstart[nb] = e;
}

// hoff[b][j] = raw per-column prefix (Σ_{b'<b} hmat[b'][j]); bstart added
// in scatter's cursor init. Chunk base = Σ_{c<chunk} bpart[c][j].
__global__ __launch_bounds__(256) void hoff2_kernel(const int* __restrict__ hmat,
                                                    const int* __restrict__ bpart,
                                                    int* __restrict__ hoff) {
    int j = blockIdx.x * 256 + threadIdx.x;
    int c = blockIdx.y;
    if (j < NB) {
        int run = 0;
        for (int k = 0; k < c; k++) run += bpart[k * NB + j];
        int b0 = c * 64;
        for (int b = b0; b < b0 + 64; b++) {
            hoff[(size_t)b * NB + j] = run;
            run += hmat[(size_t)b * NB + j];
        }
    }
}

// Scatter edges to exact bucket-sorted positions. LDS cursors, no global atomics.
__global__ __launch_bounds__(512) void scatter_kernel(const int* __restrict__ row,
                                                      const int* __restrict__ col,
                                                      const int* __restrict__ hoff,
                                                      const int* __restrict__ bstart,
                                                      unsigned* __restrict__ bucketbuf) {
    __shared__ int cur[NB];
    int b = blockIdx.x, t = threadIdx.x;
    for (int j = t; j < NB; j += 512)
        cur[j] = hoff[(size_t)b * NB + j] + bstart[j];
    __syncthreads();
    int base = b * EPB;
    for (int i = t; i < EPB; i += 512) {
        int r = row[base + i], c = col[base + i];
        int pos = atomicAdd(&cur[c >> 5], 1);  // LDS atomic
        bucketbuf[pos] = ((unsigned)r << 5) | (unsigned)(c & 31);
    }
}

// One block per bucket: LDS histogram of 32 local cols -> per-node offsets,
// dinv, and localized CSR scatter (contiguous ~2KB range, LDS cursors).
__global__ void fill2_kernel(const unsigned* __restrict__ bucketbuf, const int* __restrict__ bstart,
                             int* __restrict__ offsets, float* __restrict__ dinv,
                             int* __restrict__ src, int n, int e) {
    __shared__ unsigned ent[ENT_CAP];
    __shared__ int hist[32];
    __shared__ int cur[32];
    __shared__ int loff[32];
    int b = blockIdx.x, t = threadIdx.x;
    int s0 = bstart[b];
    int cnt = bstart[b + 1] - s0;
    if (cnt > ENT_CAP) cnt = ENT_CAP;
    if (t < 32) hist[t] = 0;
    __syncthreads();
    for (int i = t; i < cnt; i += 256) {
        unsigned v = bucketbuf[s0 + i];
        ent[i] = v;
        atomicAdd(&hist[v & 31], 1);
    }
    __syncthreads();
    if (t == 0) {
        int run = s0;
#pragma unroll
        for (int j = 0; j < 32; j++) {
            loff[j] = run;
            run += hist[j];
        }
    }
    __syncthreads();
    if (t < 32) {
        int node = b * 32 + t;
        int o = loff[t];
        offsets[node] = o;
        cur[t] = o;
        dinv[node] = rsqrtf((float)(hist[t] + 1));  // +1 self loop
    }
    if (b == 0 && t == 0) offsets[n] = e;
    __syncthreads();
    for (int i = t; i < cnt; i += 256) {
        unsigned v = ent[i];
        int pos = atomicAdd(&cur[v & 31], 1);
        src[pos] = (int)(v >> 5);
    }
}

// ---------------- per-layer kernels ----------------

// Cast + pre-scale: xs[v] = fp16(dinv[v] * emb[v]). Pre-scaling removes the
// per-edge dinv[src] gather + multiply from the agg inner loop.
__global__ void cast_kernel(const float2* __restrict__ in, const float* __restrict__ dinv,
                            __half2* __restrict__ out, int n2) {
    int i = blockIdx.x * 256 + threadIdx.x;
    if (i < n2) {
        float d = dinv[i >> 6];  // wave-uniform (64 half2 per node)
        float2 v = in[i];
        out[i] = __floats2half2_rn(d * v.x, d * v.y);
    }
}

// W pre-split for the hi/lo fp16 MFMA: WhT/WlT[l][col][k] (transposed,
// fragment-ready). w = wh + wl; A-side lo plane dropped in R15 (absmax
// unchanged at 9.77e-4 — xs-gather rounding dominates).
__global__ void wsplit_kernel(const float* __restrict__ W,
                              _Float16* __restrict__ Wh, _Float16* __restrict__ Wl) {
    int c = blockIdx.x, l = blockIdx.y, k = threadIdx.x;  // 128 threads
    float w = W[(size_t)l * 16384 + k * 128 + c];
    _Float16 h = (_Float16)w;
    float r = w - (float)h;
    Wh[(size_t)l * 16384 + c * 128 + k] = h;
    Wl[(size_t)l * 16384 + c * 128 + k] = (_Float16)r;
}

// UNFUSED aggregation. R18 change: 4 nodes per 256-thread block — wave w
// owns node blockIdx.x*4+w COMPLETELY INDEPENDENTLY (no barrier, no shared
// state; unlike the R7/R8 fused-serial failure, each wave still does exactly
// one node). Why: R18 counters showed occupancy capped at 75% (24 waves/CU)
// with VGPR=28 and LDS=0 — the 1-wave workgroup hit the CU workgroup-slot
// limit, not a resource limit. 4-wave blocks -> 8 wg/CU * 4 = 32 waves/CU.
//   a[v] = dinv[v] * ( xs[v] + sum_e xs[src_e] ), fp32 accum -> fp16 A.
// Regular (non-NT) stores: A intermediate stays L2/L3-resident (R12/R15).
__global__ __launch_bounds__(256) void agg_kernel(
    const __half2* __restrict__ xs, const int* __restrict__ offs,
    unsigned* __restrict__ Ah,
    const float* __restrict__ dinv, const int* __restrict__ src) {
    int v = blockIdx.x * 4 + (threadIdx.x >> 6);
    int f = threadIdx.x & 63;  // lane
    float dv = dinv[v];
    float2 a0 = __half22float2(xs[(size_t)v * 64 + f]);  // self term (already scaled)
    float ax = a0.x;
    float ay = a0.y;
    int i = offs[v], s1 = offs[v + 1];
    for (; i + 15 < s1; i += 16) {  // 16-deep main group
        int s[16];
#pragma unroll
        for (int j = 0; j < 16; j++) s[j] = src[i + j];
        float2 x[16];
#pragma unroll
        for (int j = 0; j < 16; j++) x[j] = __half22float2(xs[(size_t)s[j] * 64 + f]);
#pragma unroll
        for (int j = 0; j < 16; j++) {
            ax += x[j].x;
            ay += x[j].y;
        }
    }
    if (i + 7 < s1) {  // 8-deep
        int s[8];
#pragma unroll
        for (int j = 0; j < 8; j++) s[j] = src[i + j];
        float2 x[8];
#pragma unroll
        for (int j = 0; j < 8; j++) x[j] = __half22float2(xs[(size_t)s[j] * 64 + f]);
#pragma unroll
        for (int j = 0; j < 8; j++) {
            ax += x[j].x;
            ay += x[j].y;
        }
        i += 8;
    }
    if (i < s1) {  // masked tail group
        int last = s1 - 1;
        int s[8];
        float m[8];
#pragma unroll
        for (int j = 0; j < 8; j++) {
            int idx = i + j;
            bool in = idx < s1;
            s[j] = src[in ? idx : last];
            m[j] = in ? 1.0f : 0.0f;
        }
        float2 x[8];
#pragma unroll
        for (int j = 0; j < 8; j++) x[j] = __half22float2(xs[(size_t)s[j] * 64 + f]);
#pragma unroll
        for (int j = 0; j < 8; j++) {
            ax += m[j] * x[j].x;
            ay += m[j] * x[j].y;
        }
    }
    float rx = dv * ax, ry = dv * ay;
    __half2 h2 = __floats2half2_rn(rx, ry);
    Ah[(size_t)v * 64 + f] = __builtin_bit_cast(unsigned, h2);   // regular: L2/L3-resident
}

// out[M x 128] = relu(A[M x 128] @ W[128 x 128] + bias) via fp16 MFMA.
// BM=32, 3125 blocks; single fp16 A plane, W hi/lo (h = a.wh + a.wl).
// Regular loads on the A path (L2/L3 fill, R12 lesson).
__global__ __launch_bounds__(256, 6) void gemm_mfma_kernel(
    const _Float16* __restrict__ Ahp,
    const _Float16* __restrict__ Whp, const _Float16* __restrict__ Wlp,  // [col][k]
    const float* __restrict__ bias, float* __restrict__ out,
    __half2* __restrict__ xs_out, const float* __restrict__ dinv,
    int write_h, int write_out) {
    __shared__ _Float16 sA[32][136];  // [row][16 kg * 8 + 8 pad] = 8.7 KB
    int t = threadIdx.x;
    int f = t & 63;   // lane
    int w = t >> 6;   // wave 0..3 -> cols w*32 .. w*32+31
    int row0 = blockIdx.x * 32;

    // ---- stage A tile: 512 qwords (32 rows x 16), 2 per thread ----
    const u32x4* Aq = (const u32x4*)Ahp;
#pragma unroll
    for (int i = 0; i < 2; i++) {
        int qid = t + 256 * i;          // 0..511, bijective over (r, k2)
        int r = qid >> 4;               // 0..31
        int k2 = qid & 15;              // 16B k-group
        u32x4 v = Aq[(size_t)(row0 + r) * 16 + k2];   // regular load: L2/L3 fill
        *(u32x4*)&sA[r][k2 * 8] = v;
    }
    __syncthreads();

    // ---- MFMA: rows 0..31 (2 m-frags) x wave's 32 cols (2 col-frags) ----
    int lrow = f & 15, kg = f >> 4;
    f32x4 acc[2][2];  // [m][c]
#pragma unroll
    for (int m = 0; m < 2; m++)
#pragma unroll
        for (int c = 0; c < 2; c++) acc[m][c] = (f32x4){0.f, 0.f, 0.f, 0.f};

#pragma unroll
    for (int ks = 0; ks < 4; ks++) {
        int g = ks * 4 + kg;  // 8-element k-group index
        f16x8 a0 = *(const f16x8*)&sA[lrow][g * 8];
        f16x8 a1 = *(const f16x8*)&sA[16 + lrow][g * 8];
#pragma unroll
        for (int c = 0; c < 2; c++) {
            int col = w * 32 + c * 16 + lrow;
            f16x8 bh = *(const f16x8*)&Whp[(size_t)col * 128 + g * 8];
            f16x8 bl = *(const f16x8*)&Wlp[(size_t)col * 128 + g * 8];
            acc[0][c] = __builtin_amdgcn_mfma_f32_16x16x32_f16(a0, bh, acc[0][c], 0, 0, 0);
            acc[0][c] = __builtin_amdgcn_mfma_f32_16x16x32_f16(a0, bl, acc[0][c], 0, 0, 0);
            acc[1][c] = __builtin_amdgcn_mfma_f32_16x16x32_f16(a1, bh, acc[1][c], 0, 0, 0);
            acc[1][c] = __builtin_amdgcn_mfma_f32_16x16x32_f16(a1, bl, acc[1][c], 0, 0, 0);
        }
    }

    // ---- epilogue: bias + relu; C/D frag: col=lane&15, row=(lane>>4)*4+reg ----
    float bcol[2];
    bcol[0] = bias[w * 32 + 0 * 16 + lrow];
    bcol[1] = bias[w * 32 + 1 * 16 + lrow];
#pragma unroll
    for (int m = 0; m < 2; m++) {
        int rbase = row0 + m * 16 + kg * 4;
#pragma unroll
        for (int j = 0; j < 4; j++) {
            int rowi = rbase + j;
            float dvr = write_h ? dinv[rowi] : 0.f;
#pragma unroll
            for (int c = 0; c < 2; c++) {
                float o = fmaxf(acc[m][c][j] + bcol[c], 0.f);
                float o2 = __shfl_xor(o, 1);  // partner col (lane^1): same row, col^1
                int col = w * 32 + c * 16 + lrow;
                if (write_out)
                    __builtin_nontemporal_store(o, out + (size_t)rowi * 128 + col);
                if (write_h && !(f & 1))
                    xs_out[(size_t)rowi * 64 + (col >> 1)] =
                        __floats2half2_rn(dvr * o, dvr * o2);
            }
        }
    }
}

// ---------------- launch ----------------

extern "C" void kernel_launch(void* const* d_in, const int* in_sizes, int n_in,
                              void* d_out, int out_size, void* d_ws, size_t ws_size,
                              hipStream_t stream) {
    const int* edge = (const int*)d_in[0];   // [2, E] int32
    const float* emb = (const float*)d_in[1];
    const float* Ws = (const float*)d_in[2]; // [L, D, D]
    const float* bs = (const float*)d_in[3]; // [L, D]
    float* out = (float*)d_out;

    const int n = N_NODES, e = N_EDGES;
    const int* row = edge;       // sources
    const int* col = edge + e;   // targets

    char* p = (char*)d_ws;
    _Float16* Ah = (_Float16*)p;
    int* hmat = (int*)p;                      // aliases Ah (dead until first agg)
    int* hoff = hmat + (size_t)NBLK_E * NB;   // 6.4 MB each
    int* bpart = hoff + (size_t)NBLK_E * NB;  // 100 KB
    p += (size_t)n * D * 2;                   // 25.6 MB  (single fp16 A plane)
    __half2* xs = (__half2*)p;                // 25.6 MB (pre-scaled fp16 features)
    unsigned* bucketbuf = (unsigned*)p;       // aliases xs: dead before cast runs
    p += (size_t)n * D * 2;
    int* csr_src  = (int*)p;    p += (size_t)e * 4;           // 6.4 MB
    float* dinv   = (float*)p;  p += (size_t)n * 4;
    int* offsets  = (int*)p;    p += (size_t)(n + 1) * 4;
    int* bstart   = (int*)p;    p += (size_t)(NB + 1) * 4;
    _Float16* WhT = (_Float16*)p; p += (size_t)NLAYERS * D * D * 2;  // 98 KB
    _Float16* WlT = (_Float16*)p; p += (size_t)NLAYERS * D * D * 2;  // 98 KB

    hist1_kernel<<<NBLK_E, 512, 0, stream>>>(col, hmat);
    bpart_kernel<<<dim3(13, NCHUNK), 256, 0, stream>>>(hmat, bpart);
    bscan_kernel<<<1, 1024, 0, stream>>>(bpart, bstart, NB, e);
    hoff2_kernel<<<dim3(13, NCHUNK), 256, 0, stream>>>(hmat, bpart, hoff);
    scatter_kernel<<<NBLK_E, 512, 0, stream>>>(row, col, hoff, bstart, bucketbuf);
    fill2_kernel<<<NB, 256, 0, stream>>>(bucketbuf, bstart, offsets, dinv, csr_src, n, e);
    wsplit_kernel<<<dim3(128, NLAYERS), 128, 0, stream>>>(Ws, WhT, WlT);

    int n2 = n * 64;  // half2 count
    cast_kernel<<<(n2 + 255) / 256, 256, 0, stream>>>((const float2*)emb, dinv, xs, n2);

    for (int l = 0; l < NLAYERS; l++) {
        agg_kernel<<<n / 4, 256, 0, stream>>>(xs, offsets, (unsigned*)Ah, dinv, csr_src);
        gemm_mfma_kernel<<<n / 32, 256, 0, stream>>>(
            Ah, WhT + (size_t)l * D * D, WlT + (size_t)l * D * D,
            bs + (size_t)l * D, out, xs, dinv,
            (l < NLAYERS - 1) ? 1 : 0, (l == NLAYERS - 1) ? 1 : 0);
    }
}